// Round 8
// baseline (4616.611 us; speedup 1.0000x reference)
//
#include <hip/hip_runtime.h>
#include <cstddef>

// ---------------------------------------------------------------------------
// PointNet++ (B=4, N0=4096, NIN=16, NH=128, NOUT=2, DEPTH=3, K=64, R=2, KNN=3)
// fp32. Selection paths (FPS argmax, radius top-K, 3-NN) use non-contracted
// fp32 ops + first-index tie-breaks to match the reference bit-for-bit.
// FPS: round-5 structure + coords-in-slot (owner lane writes value/index/
// coords; winner coords recovered via readlane from slot registers -- no
// dependent LDS read at the end of the step). NT=256, one barrier/step.
// SA MLP = compacted batched GEMM over valid (center,point) pairs with
// atomicMax (uint bits, values >= 0) scatter for the max-aggregation.
// ---------------------------------------------------------------------------

#define EPSF 1e-5f

__device__ __forceinline__ float d2_rn(float dx, float dy, float dz) {
    return __fadd_rn(__fadd_rn(__fmul_rn(dx, dx), __fmul_rn(dy, dy)), __fmul_rn(dz, dz));
}

template <int CTRL, int RMASK>
__device__ __forceinline__ float dpp_max_f32(float v) {
    int o = __builtin_amdgcn_update_dpp(__float_as_int(v), __float_as_int(v),
                                        CTRL, RMASK, 0xf, false);
    return fmaxf(v, __int_as_float(o));
}

__device__ __forceinline__ float readlane_f(float v, int l) {
    return __int_as_float(__builtin_amdgcn_readlane(__float_as_int(v), l));
}

// ---------------- K1: lin_in  xb = relu(x @ W + b), rows=16384 --------------
__global__ __launch_bounds__(128) void lin_in_kernel(
    const float* __restrict__ x, const float* __restrict__ w,
    const float* __restrict__ b, float* __restrict__ xb) {
    __shared__ float sx[16];
    int row = blockIdx.x;
    int t = threadIdx.x;
    if (t < 16) sx[t] = x[row * 16 + t];
    __syncthreads();
    float acc = b[t];
#pragma unroll
    for (int k = 0; k < 16; ++k) acc = fmaf(sx[k], w[k * 128 + t], acc);
    xb[row * 128 + t] = fmaxf(acc, 0.0f);
}

// ---------------- K2: FPS, coords-in-slot (bisect: only change vs round 7) --
template <int N, int NT>
__global__ __launch_bounds__(NT) void fps_kernel(
    const float* __restrict__ pts, float* __restrict__ q, int m) {
    constexpr int PPT = N / NT;
    constexpr int NW = NT / 64;
    __shared__ float s_px[N], s_py[N], s_pz[N];
    __shared__ int   s_qi[N / 2];
    __shared__ __align__(16) float s_slot[2][NW][8];   // v, idx, x, y, z
    const int b = blockIdx.x, t = threadIdx.x;
    const int wave = t >> 6, lane = t & 63;
    const int base = t * PPT;                        // blocked assignment
    const float* P = pts + (size_t)b * N * 3;
    float rx[PPT], ry[PPT], rz[PPT], dmin[PPT];
#pragma unroll
    for (int j = 0; j < PPT; ++j) {
        int i = base + j;
        float x = P[i * 3], y = P[i * 3 + 1], z = P[i * 3 + 2];
        rx[j] = x; ry[j] = y; rz[j] = z; dmin[j] = 1e30f;
        s_px[i] = x; s_py[i] = y; s_pz[i] = z;
    }
    float lx = P[0], ly = P[1], lz = P[2];
    if (t == 0) s_qi[0] = 0;

    for (int step = 1; step < m; ++step) {
        // ---- dmin update + per-thread argmax w/ coords (first j via strict >) --
        float bv = -1.0f; int bi = 0;
        float bx = 0.f, by = 0.f, bz = 0.f;
#pragma unroll
        for (int j = 0; j < PPT; ++j) {
            float d = d2_rn(rx[j] - lx, ry[j] - ly, rz[j] - lz);
            float dm = fminf(dmin[j], d);
            dmin[j] = dm;
            bool take = dm > bv;
            bv = take ? dm : bv;
            bi = take ? base + j : bi;
            bx = take ? rx[j] : bx;
            by = take ? ry[j] : by;
            bz = take ? rz[j] : bz;
        }

        // ---- in-wave value-only f32 DPP max tree -> lane 63 ----
        float v = bv;
        v = dpp_max_f32<0x111, 0xf>(v);   // row_shr:1
        v = dpp_max_f32<0x112, 0xf>(v);   // row_shr:2
        v = dpp_max_f32<0x114, 0xf>(v);   // row_shr:4
        v = dpp_max_f32<0x118, 0xf>(v);   // row_shr:8
        v = dpp_max_f32<0x142, 0xa>(v);   // row_bcast:15
        v = dpp_max_f32<0x143, 0xc>(v);   // row_bcast:31
        const float mv = __int_as_float(__builtin_amdgcn_readlane(__float_as_int(v), 63));
        // lowest matching lane == lowest index (blocked assignment, bit-exact max)
        unsigned long long mb = __ballot(bv == mv);
        const int wl = __ffsll((long long)mb) - 1;

        const int p = step & 1;
        if (lane == wl) {                 // owner writes value+index+coords
            float* s = s_slot[p][wave];
            *(float4*)s = make_float4(mv, __int_as_float(bi), bx, by);
            s[4] = bz;
        }
        __syncthreads();

        // ---- cross-wave: lane-parallel slot read + small tree + ballot ----
        const float* sl = s_slot[p][lane & (NW - 1)];
        float4 A = *(const float4*)sl;    // v, idx, x, y
        float  Z = sl[4];
        float gvt = A.x;
        gvt = dpp_max_f32<0x111, 0xf>(gvt);
        gvt = dpp_max_f32<0x112, 0xf>(gvt);
        if (NW == 8) gvt = dpp_max_f32<0x114, 0xf>(gvt);
        const float gm = __int_as_float(
            __builtin_amdgcn_readlane(__float_as_int(gvt), NW - 1));
        unsigned long long gb = __ballot((lane < NW) && (A.x == gm));
        const int gl = __ffsll((long long)gb) - 1;        // lowest slot == lowest index
        const int gi = __builtin_amdgcn_readlane(__float_as_int(A.y), gl);
        lx = readlane_f(A.z, gl);
        ly = readlane_f(A.w, gl);
        lz = readlane_f(Z, gl);
        if (t == 0) s_qi[step] = gi;
    }
    __syncthreads();
    for (int e = t; e < m; e += NT) {
        int gi = s_qi[e];
        size_t o = ((size_t)b * m + e) * 3;
        q[o] = s_px[gi]; q[o + 1] = s_py[gi]; q[o + 2] = s_pz[gi];
    }
}

// ---------------- K3: zero h1|h2|h3 (contiguous) + all pair counters --------
__global__ void zero_all_kernel(float* __restrict__ buf, int n,
                                unsigned* __restrict__ ctrs) {
    int i = blockIdx.x * 256 + threadIdx.x;
    if (i < n) buf[i] = 0.0f;
    if (i < 3) ctrs[i * 16] = 0u;
}

// ---------------- K4: radius-ball K=64 selection -> compacted pair list -----
template <int CHUNK, int WAVES>
__global__ void nbr_kernel(const float* __restrict__ pts, const float* __restrict__ q,
                           int2* __restrict__ pairs, unsigned* __restrict__ counter,
                           int n, int m) {
    __shared__ float dst[WAVES * CHUNK * 64];
    const int w = threadIdx.x >> 6, lane = threadIdx.x & 63;
    const int c = blockIdx.x * WAVES + w;
    const int b = c / m;
    float* D = dst + w * CHUNK * 64;
    const float* P = pts + (size_t)b * n * 3;
    const float qx = q[(size_t)c * 3 + 0];
    const float qy = q[(size_t)c * 3 + 1];
    const float qz = q[(size_t)c * 3 + 2];
    for (int s = 0; s < CHUNK; ++s) {
        int i = s * 64 + lane;
        float d2 = d2_rn(P[i * 3] - qx, P[i * 3 + 1] - qy, P[i * 3 + 2] - qz);
        D[i] = (d2 <= 4.0f) ? d2 : 1e30f;   // RADIUS^2 = 4
    }
    int my_g = -1;
    int cnt = 0;
    for (int round = 0; round < 64; ++round) {
        float bv = 3e38f;
        int bi = 0x7fffffff;
        for (int s = 0; s < CHUNK; ++s) {
            int i = s * 64 + lane;
            float v = D[i];
            if (v < bv) { bv = v; bi = i; }   // strict <: lowest-index tie-break
        }
#pragma unroll
        for (int off = 32; off >= 1; off >>= 1) {
            float ov = __shfl_xor(bv, off, 64);
            int   oi = __shfl_xor(bi, off, 64);
            if (ov < bv || (ov == bv && oi < bi)) { bv = ov; bi = oi; }
        }
        if (bv > 1e29f) break;               // only invalid/removed remain (uniform)
        if (round == lane) my_g = bi;
        if (lane == (bi & 63)) D[bi] = 3e38f;
        ++cnt;
    }
    unsigned base = 0;
    if (lane == 0) base = atomicAdd(counter, (unsigned)cnt);
    base = (unsigned)__shfl((int)base, 0, 64);
    if (lane < cnt) pairs[base + lane] = make_int2(c, my_g);
}

// ---------------- K5: fused SA MLP over compacted rows ----------------------
__global__ __launch_bounds__(256) void sa_fused_kernel(
    const float* __restrict__ xx, const float* __restrict__ pts,
    const float* __restrict__ q, const int2* __restrict__ pairs,
    const unsigned* __restrict__ vcount,
    const float* __restrict__ w1, const float* __restrict__ b1,
    const float* __restrict__ g1, const float* __restrict__ be1,
    const float* __restrict__ w2, const float* __restrict__ b2,
    const float* __restrict__ g2, const float* __restrict__ be2,
    float* __restrict__ hout, int lm, int ln) {
    __shared__ __align__(16) float shA[64][132];   // gather -> H1 -> out (reused)
    __shared__ __align__(16) float shW[32][132];
    __shared__ int sh_c[64], sh_g[64];
    const int t = threadIdx.x;
    const int V = (int)*vcount;
    const int r0 = blockIdx.x * 64;
    if (r0 >= V) return;
    if (t < 64) {
        int r = r0 + t;
        if (r < V) { int2 p = pairs[r]; sh_c[t] = p.x; sh_g[t] = p.y; }
        else { sh_c[t] = -1; sh_g[t] = 0; }
    }
    __syncthreads();

    // ---- gather A: 64 rows x 132 cols (33 float4 chunks per row) ----
    for (int e = t; e < 64 * 33; e += 256) {
        int row = e / 33, cid = e - row * 33;
        int c = sh_c[row];
        float4 v = make_float4(0.f, 0.f, 0.f, 0.f);
        if (c >= 0) {
            int g = sh_g[row];
            int b = c >> lm;
            size_t pt = ((size_t)(b << ln) + g);
            if (cid < 32) {
                v = *(const float4*)(xx + (pt << 7) + cid * 4);
            } else {
                const float* P = pts + pt * 3;
                const float* Q = q + (size_t)c * 3;
                v.x = P[0] - Q[0]; v.y = P[1] - Q[1]; v.z = P[2] - Q[2]; v.w = 0.f;
            }
        }
        *(float4*)&shA[row][cid * 4] = v;
    }
    __syncthreads();

    const float invs = 1.0f / sqrtf(1.0f + EPSF);
    const int tr = t >> 4, tc = t & 15;       // rows 4tr..4tr+3, cols 8tc..8tc+7
    const int xrow = t >> 2, xcol = t & 3;    // extra cols 128..131
    float acc[32];
#pragma unroll
    for (int i = 0; i < 32; ++i) acc[i] = 0.0f;
    float accx = 0.0f;

    // ---- layer 1: K=132 (rows/cols >=131 zero-padded) ----
    for (int k0 = 0; k0 < 132; k0 += 32) {
        const int kc = (132 - k0 < 32) ? (132 - k0) : 32;
        for (int e = t; e < kc * 132; e += 256) {
            int kk = e / 132, j = e - kk * 132;
            int k = k0 + kk;
            shW[kk][j] = (k < 131 && j < 131) ? w1[k * 131 + j] : 0.0f;
        }
        __syncthreads();
        for (int kk = 0; kk < kc; ++kk) {
            const int k = k0 + kk;
            float a0 = shA[4 * tr + 0][k], a1 = shA[4 * tr + 1][k];
            float a2 = shA[4 * tr + 2][k], a3 = shA[4 * tr + 3][k];
            const float4 w0 = *(const float4*)&shW[kk][8 * tc];
            const float4 w1v = *(const float4*)&shW[kk][8 * tc + 4];
            const float wa[8] = {w0.x, w0.y, w0.z, w0.w, w1v.x, w1v.y, w1v.z, w1v.w};
#pragma unroll
            for (int j = 0; j < 8; ++j) {
                acc[0 * 8 + j] = fmaf(a0, wa[j], acc[0 * 8 + j]);
                acc[1 * 8 + j] = fmaf(a1, wa[j], acc[1 * 8 + j]);
                acc[2 * 8 + j] = fmaf(a2, wa[j], acc[2 * 8 + j]);
                acc[3 * 8 + j] = fmaf(a3, wa[j], acc[3 * 8 + j]);
            }
            accx = fmaf(shA[xrow][k], shW[kk][128 + xcol], accx);
        }
        __syncthreads();
    }
    // epilogue 1 -> H1 into shA
#pragma unroll
    for (int i = 0; i < 4; ++i)
#pragma unroll
        for (int j = 0; j < 8; ++j) {
            int col = 8 * tc + j;
            float z = fmaxf(acc[i * 8 + j] + b1[col], 0.0f);
            shA[4 * tr + i][col] = g1[col] * z * invs + be1[col];
        }
    if (xcol < 3) {
        int col = 128 + xcol;
        float z = fmaxf(accx + b1[col], 0.0f);
        shA[xrow][col] = g1[col] * z * invs + be1[col];
    } else {
        shA[xrow][131] = 0.0f;   // zero K-pad col (w2 row 131 is also zeroed)
    }

    // ---- layer 2: 132 -> 128 ----
#pragma unroll
    for (int i = 0; i < 32; ++i) acc[i] = 0.0f;
    for (int k0 = 0; k0 < 132; k0 += 32) {
        const int kc = (132 - k0 < 32) ? (132 - k0) : 32;
        for (int e = t; e < kc * 132; e += 256) {
            int kk = e / 132, j = e - kk * 132;
            int k = k0 + kk;
            shW[kk][j] = (k < 131 && j < 128) ? w2[k * 128 + j] : 0.0f;
        }
        __syncthreads();
        for (int kk = 0; kk < kc; ++kk) {
            const int k = k0 + kk;
            float a0 = shA[4 * tr + 0][k], a1 = shA[4 * tr + 1][k];
            float a2 = shA[4 * tr + 2][k], a3 = shA[4 * tr + 3][k];
            const float4 w0 = *(const float4*)&shW[kk][8 * tc];
            const float4 w1v = *(const float4*)&shW[kk][8 * tc + 4];
            const float wa[8] = {w0.x, w0.y, w0.z, w0.w, w1v.x, w1v.y, w1v.z, w1v.w};
#pragma unroll
            for (int j = 0; j < 8; ++j) {
                acc[0 * 8 + j] = fmaf(a0, wa[j], acc[0 * 8 + j]);
                acc[1 * 8 + j] = fmaf(a1, wa[j], acc[1 * 8 + j]);
                acc[2 * 8 + j] = fmaf(a2, wa[j], acc[2 * 8 + j]);
                acc[3 * 8 + j] = fmaf(a3, wa[j], acc[3 * 8 + j]);
            }
        }
        __syncthreads();
    }
    // epilogue 2 -> out into shA (cols 0..127)
#pragma unroll
    for (int i = 0; i < 4; ++i)
#pragma unroll
        for (int j = 0; j < 8; ++j) {
            int col = 8 * tc + j;
            float z = fmaxf(acc[i * 8 + j] + b2[col], 0.0f);
            shA[4 * tr + i][col] = g2[col] * z * invs + be2[col];
        }
    __syncthreads();

    // ---- segmented max over contiguous same-center rows + atomic scatter ----
    if (t < 128) {
        const int col = t;
        float run = -1.0f;
        int cur = sh_c[0];
        for (int row = 0; row < 64; ++row) {
            int c = sh_c[row];
            if (c != cur) {
                if (cur >= 0)
                    atomicMax((unsigned*)&hout[((size_t)cur << 7) + col], __float_as_uint(run));
                run = -1.0f; cur = c;
            }
            run = fmaxf(run, shA[row][col]);
        }
        if (cur >= 0)
            atomicMax((unsigned*)&hout[((size_t)cur << 7) + col], __float_as_uint(run));
    }
}

// ---------------- K6a: 3-NN search + inverse-d2 weights --------------------
__global__ __launch_bounds__(256) void knn_kernel(
    const float* __restrict__ pf, const float* __restrict__ pc,
    int* __restrict__ kidx, float* __restrict__ kw, int nf, int nc) {
    const int tg = blockIdx.x * 256 + threadIdx.x;
    const int b = tg / nf;
    const float* F = pf + (size_t)tg * 3;
    const float fx = F[0], fy = F[1], fz = F[2];
    const float* C = pc + (size_t)b * nc * 3;
    float b0 = 1e30f, b1 = 1e30f, b2 = 1e30f;
    int i0 = 0, i1 = 0, i2 = 0;
    for (int j = 0; j < nc; ++j) {
        float d2 = d2_rn(C[j * 3] - fx, C[j * 3 + 1] - fy, C[j * 3 + 2] - fz);
        if (d2 < b0)      { b2 = b1; i2 = i1; b1 = b0; i1 = i0; b0 = d2; i0 = j; }
        else if (d2 < b1) { b2 = b1; i2 = i1; b1 = d2; i1 = j; }
        else if (d2 < b2) { b2 = d2; i2 = j; }
    }
    float w0 = 1.0f / fmaxf(b0, 1e-16f);
    float w1 = 1.0f / fmaxf(b1, 1e-16f);
    float w2 = 1.0f / fmaxf(b2, 1e-16f);
    float inv = 1.0f / (w0 + w1 + w2);
    size_t o = (size_t)tg * 3;
    kidx[o] = i0; kidx[o + 1] = i1; kidx[o + 2] = i2;
    kw[o] = w0 * inv; kw[o + 1] = w1 * inv; kw[o + 2] = w2 * inv;
}

// ---------------- K6b: interpolate + concat skip -> cat[f][256] -------------
__global__ __launch_bounds__(256) void interp_cat_kernel(
    const float* __restrict__ xc, const float* __restrict__ xs,
    const int* __restrict__ kidx, const float* __restrict__ kw,
    float* __restrict__ cat, int nf, int nc) {
    const int f = blockIdx.x;
    const int t = threadIdx.x;
    const int b = f / nf;
    const size_t o = (size_t)f * 3;
    if (t < 128) {
        int i0 = kidx[o], i1 = kidx[o + 1], i2 = kidx[o + 2];
        float w0 = kw[o], w1 = kw[o + 1], w2 = kw[o + 2];
        const float* X = xc + (size_t)b * nc * 128;
        float y = w0 * X[(size_t)i0 * 128 + t] + w1 * X[(size_t)i1 * 128 + t] +
                  w2 * X[(size_t)i2 * 128 + t];
        cat[(size_t)f * 256 + t] = y;
    } else {
        cat[(size_t)f * 256 + t] = xs[(size_t)f * 128 + (t - 128)];
    }
}

// ---------------- K7: generic GEMM + bias + relu + BN epilogue --------------
__global__ __launch_bounds__(256) void gemm_bn_kernel(
    const float* __restrict__ A, const float* __restrict__ W,
    const float* __restrict__ bias, const float* __restrict__ g,
    const float* __restrict__ be, float* __restrict__ C, int Kin, int Cout) {
    __shared__ __align__(16) float shA[64][33];
    __shared__ __align__(16) float shB[32][68];
    const int t = threadIdx.x;
    const int r0 = blockIdx.x * 64;
    const int c0 = blockIdx.y * 64;
    const int tr = t >> 4, tc = t & 15;
    const float invs = 1.0f / sqrtf(1.0f + EPSF);
    float acc[16];
#pragma unroll
    for (int i = 0; i < 16; ++i) acc[i] = 0.0f;
    for (int k0 = 0; k0 < Kin; k0 += 32) {
#pragma unroll
        for (int e = t; e < 2048; e += 256) {
            int r = e >> 5, kk = e & 31;
            shA[r][kk] = A[(size_t)(r0 + r) * Kin + k0 + kk];
        }
#pragma unroll
        for (int e = t; e < 2048; e += 256) {
            int kk = e >> 6, cc = e & 63;
            shB[kk][cc] = W[(size_t)(k0 + kk) * Cout + c0 + cc];
        }
        __syncthreads();
        for (int kk = 0; kk < 32; ++kk) {
            float av[4];
#pragma unroll
            for (int i = 0; i < 4; ++i) av[i] = shA[4 * tr + i][kk];
            const float4 wv = *(const float4*)&shB[kk][4 * tc];
            const float wa[4] = {wv.x, wv.y, wv.z, wv.w};
#pragma unroll
            for (int i = 0; i < 4; ++i)
#pragma unroll
                for (int jj = 0; jj < 4; ++jj)
                    acc[i * 4 + jj] = fmaf(av[i], wa[jj], acc[i * 4 + jj]);
        }
        __syncthreads();
    }
#pragma unroll
    for (int i = 0; i < 4; ++i)
#pragma unroll
        for (int jj = 0; jj < 4; ++jj) {
            int col = c0 + 4 * tc + jj;
            float z = fmaxf(acc[i * 4 + jj] + bias[col], 0.0f);
            C[(size_t)(r0 + 4 * tr + i) * Cout + col] = g[col] * z * invs + be[col];
        }
}

// ---------------- K8: final 128 -> 2 layer ----------------------------------
__global__ __launch_bounds__(256) void lo2_kernel(
    const float* __restrict__ in, const float* __restrict__ w,
    const float* __restrict__ b, const float* __restrict__ g,
    const float* __restrict__ be, float* __restrict__ out) {
    __shared__ float sw[256];
    const int t = threadIdx.x;
    sw[t] = w[t];
    __syncthreads();
    const int row = blockIdx.x * 256 + t;
    const float invs = 1.0f / sqrtf(1.0f + EPSF);
    float a0 = b[0], a1 = b[1];
    const float* R = in + (size_t)row * 128;
    for (int k = 0; k < 128; ++k) {
        float a = R[k];
        a0 = fmaf(a, sw[k * 2], a0);
        a1 = fmaf(a, sw[k * 2 + 1], a1);
    }
    a0 = fmaxf(a0, 0.0f);
    a1 = fmaxf(a1, 0.0f);
    out[(size_t)row * 2]     = g[0] * a0 * invs + be[0];
    out[(size_t)row * 2 + 1] = g[1] * a1 * invs + be[1];
}

// ---------------------------------------------------------------------------
extern "C" void kernel_launch(void* const* d_in, const int* in_sizes, int n_in,
                              void* d_out, int out_size, void* d_ws, size_t ws_size,
                              hipStream_t stream) {
    const float* x      = (const float*)d_in[0];
    const float* pos    = (const float*)d_in[1];
    const float* lin_w  = (const float*)d_in[3];
    const float* lin_b  = (const float*)d_in[4];
    const float* sa_w1  = (const float*)d_in[5];
    const float* sa_b1  = (const float*)d_in[6];
    const float* sa_g1  = (const float*)d_in[7];
    const float* sa_be1 = (const float*)d_in[8];
    const float* sa_w2  = (const float*)d_in[9];
    const float* sa_b2  = (const float*)d_in[10];
    const float* sa_g2  = (const float*)d_in[11];
    const float* sa_be2 = (const float*)d_in[12];
    const float* fp_w1  = (const float*)d_in[13];
    const float* fp_b1  = (const float*)d_in[14];
    const float* fp_g1  = (const float*)d_in[15];
    const float* fp_be1 = (const float*)d_in[16];
    const float* fp_w2  = (const float*)d_in[17];
    const float* fp_b2  = (const float*)d_in[18];
    const float* fp_g2  = (const float*)d_in[19];
    const float* fp_be2 = (const float*)d_in[20];
    const float* lo_w1  = (const float*)d_in[21];
    const float* lo_b1  = (const float*)d_in[22];
    const float* lo_g1  = (const float*)d_in[23];
    const float* lo_be1 = (const float*)d_in[24];
    const float* lo_w2  = (const float*)d_in[25];
    const float* lo_b2  = (const float*)d_in[26];
    const float* lo_g2  = (const float*)d_in[27];
    const float* lo_be2 = (const float*)d_in[28];

    float* ws = (float*)d_ws;
    size_t off = 0;
    auto alloc = [&](size_t n) { float* p = ws + off; off += n; return p; };
    float* xb    = alloc(4 * 4096 * 128);
    float* q1    = alloc(4 * 2048 * 3);
    float* q2    = alloc(4 * 1024 * 3);
    float* q3    = alloc(4 * 512 * 3);
    float* h1    = alloc(4 * 2048 * 128);   // h1,h2,h3 contiguous for zero_all
    float* h2    = alloc(4 * 1024 * 128);
    float* h3    = alloc(4 * 512 * 128);
    int2* pairs1 = (int2*)alloc(4 * 2048 * 64 * 2);
    int2* pairs2 = (int2*)alloc(4 * 1024 * 64 * 2);
    int2* pairs3 = (int2*)alloc(4 * 512 * 64 * 2);
    unsigned* ctrs = (unsigned*)alloc(64);   // [0],[16],[32] per level
    int* kidx    = (int*)alloc(4 * 4096 * 3);
    float* kw    = alloc(4 * 4096 * 3);
    float* cat   = alloc(4 * 4096 * 256);
    float* mbuf  = alloc(4 * 4096 * 256);
    float* xfA   = alloc(4 * 4096 * 128);
    float* xfB   = alloc(4 * 4096 * 128);
    if (ws_size < off * sizeof(float)) return;

    // h1|h2|h3 span = 4*(2048+1024+512)*128 floats
    const int hz = 4 * 3584 * 128;
    zero_all_kernel<<<(hz + 255) / 256, 256, 0, stream>>>(h1, hz, ctrs);
    lin_in_kernel<<<16384, 128, 0, stream>>>(x, lin_w, lin_b, xb);

    // ---- SA level 0: 4096 -> 2048 ----
    fps_kernel<4096, 256><<<4, 256, 0, stream>>>(pos, q1, 2048);
    nbr_kernel<64, 2><<<4096, 128, 0, stream>>>(pos, q1, pairs1, ctrs + 0, 4096, 2048);
    sa_fused_kernel<<<8192, 256, 0, stream>>>(xb, pos, q1, pairs1, ctrs + 0,
        sa_w1, sa_b1, sa_g1, sa_be1, sa_w2, sa_b2, sa_g2, sa_be2, h1, 11, 12);

    // ---- SA level 1: 2048 -> 1024 ----
    fps_kernel<2048, 256><<<4, 256, 0, stream>>>(q1, q2, 1024);
    nbr_kernel<32, 4><<<1024, 256, 0, stream>>>(q1, q2, pairs2, ctrs + 16, 2048, 1024);
    sa_fused_kernel<<<4096, 256, 0, stream>>>(h1, q1, q2, pairs2, ctrs + 16,
        sa_w1 + 131 * 131, sa_b1 + 131, sa_g1 + 131, sa_be1 + 131,
        sa_w2 + 131 * 128, sa_b2 + 128, sa_g2 + 128, sa_be2 + 128, h2, 10, 11);

    // ---- SA level 2: 1024 -> 512 ----
    fps_kernel<1024, 256><<<4, 256, 0, stream>>>(q2, q3, 512);
    nbr_kernel<16, 4><<<512, 256, 0, stream>>>(q2, q3, pairs3, ctrs + 32, 1024, 512);
    sa_fused_kernel<<<2048, 256, 0, stream>>>(h2, q2, q3, pairs3, ctrs + 32,
        sa_w1 + 2 * 131 * 131, sa_b1 + 2 * 131, sa_g1 + 2 * 131, sa_be1 + 2 * 131,
        sa_w2 + 2 * 131 * 128, sa_b2 + 2 * 128, sa_g2 + 2 * 128, sa_be2 + 2 * 128, h3, 9, 10);

    // ---- FP step 0 (mi=2): 512 -> 1024 ----
    knn_kernel<<<(4 * 1024) / 256, 256, 0, stream>>>(q2, q3, kidx, kw, 1024, 512);
    interp_cat_kernel<<<4 * 1024, 256, 0, stream>>>(h3, h2, kidx, kw, cat, 1024, 512);
    gemm_bn_kernel<<<dim3(4096 / 64, 4), 256, 0, stream>>>(cat,
        fp_w1 + 2 * 256 * 256, fp_b1 + 2 * 256, fp_g1 + 2 * 256, fp_be1 + 2 * 256,
        mbuf, 256, 256);
    gemm_bn_kernel<<<dim3(4096 / 64, 2), 256, 0, stream>>>(mbuf,
        fp_w2 + 2 * 256 * 128, fp_b2 + 2 * 128, fp_g2 + 2 * 128, fp_be2 + 2 * 128,
        xfA, 256, 128);

    // ---- FP step 1 (mi=1): 1024 -> 2048 ----
    knn_kernel<<<(4 * 2048) / 256, 256, 0, stream>>>(q1, q2, kidx, kw, 2048, 1024);
    interp_cat_kernel<<<4 * 2048, 256, 0, stream>>>(xfA, h1, kidx, kw, cat, 2048, 1024);
    gemm_bn_kernel<<<dim3(8192 / 64, 4), 256, 0, stream>>>(cat,
        fp_w1 + 256 * 256, fp_b1 + 256, fp_g1 + 256, fp_be1 + 256,
        mbuf, 256, 256);
    gemm_bn_kernel<<<dim3(8192 / 64, 2), 256, 0, stream>>>(mbuf,
        fp_w2 + 256 * 128, fp_b2 + 128, fp_g2 + 128, fp_be2 + 128,
        xfB, 256, 128);

    // ---- FP step 2 (mi=0): 2048 -> 4096 ----
    knn_kernel<<<(4 * 4096) / 256, 256, 0, stream>>>(pos, q1, kidx, kw, 4096, 2048);
    interp_cat_kernel<<<4 * 4096, 256, 0, stream>>>(xfB, xb, kidx, kw, cat, 4096, 2048);
    gemm_bn_kernel<<<dim3(16384 / 64, 4), 256, 0, stream>>>(cat,
        fp_w1, fp_b1, fp_g1, fp_be1, mbuf, 256, 256);
    gemm_bn_kernel<<<dim3(16384 / 64, 2), 256, 0, stream>>>(mbuf,
        fp_w2, fp_b2, fp_g2, fp_be2, xfA, 256, 128);

    // ---- output MLP ----
    gemm_bn_kernel<<<dim3(16384 / 64, 2), 256, 0, stream>>>(xfA,
        lo_w1, lo_b1, lo_g1, lo_be1, mbuf, 128, 128);
    lo2_kernel<<<16384 / 256, 256, 0, stream>>>(mbuf, lo_w2, lo_b2, lo_g2, lo_be2,
        (float*)d_out);
}

// Round 9
// 3830.209 us; speedup vs baseline: 1.2053x; 1.2053x over previous
//
#include <hip/hip_runtime.h>
#include <cstddef>

// ---------------------------------------------------------------------------
// PointNet++ (B=4, N0=4096, NIN=16, NH=128, NOUT=2, DEPTH=3, K=64, R=2, KNN=3)
// fp32. Selection paths (FPS argmax, radius top-K, 3-NN) use non-contracted
// fp32 ops + first-index tie-breaks to match the reference bit-for-bit.
// FPS math = round-7 proven structure (1283us @ L0), unchanged.
// NEW: multi-role stage kernels exploit dependency width -- fps level i+1
// runs concurrently (different blocks, same kernel) with nbr/sa of level i.
// All roles in a stage have complete inputs at stage start: no flags/fences.
// fps waves take s_setprio 3 to protect their serial latency chain.
// ---------------------------------------------------------------------------

#define EPSF 1e-5f

__device__ __forceinline__ float d2_rn(float dx, float dy, float dz) {
    return __fadd_rn(__fadd_rn(__fmul_rn(dx, dx), __fmul_rn(dy, dy)), __fmul_rn(dz, dz));
}

template <int CTRL, int RMASK>
__device__ __forceinline__ float dpp_max_f32(float v) {
    int o = __builtin_amdgcn_update_dpp(__float_as_int(v), __float_as_int(v),
                                        CTRL, RMASK, 0xf, false);
    return fmaxf(v, __int_as_float(o));
}

// ---------------- FPS role (round-7 math verbatim; LDS via pointer) ---------
template <int N, int NT>
__device__ void fps_role(const float* __restrict__ pts, float* __restrict__ q,
                         const int m, const int b, char* smem) {
    constexpr int PPT = N / NT;
    constexpr int NW = NT / 64;
    float* s_px = (float*)smem;
    float* s_py = s_px + N;
    float* s_pz = s_py + N;
    int*   s_qi = (int*)(s_pz + N);
    float2* s_slot = (float2*)(s_qi + N / 2);   // [2][NW]
    const int t = threadIdx.x;
    const int wave = t >> 6, lane = t & 63;
    const int base = t * PPT;                    // blocked assignment
    const float* P = pts + (size_t)b * N * 3;
    asm volatile("s_setprio 3");                 // protect serial chain
    float rx[PPT], ry[PPT], rz[PPT], dmin[PPT];
#pragma unroll
    for (int j = 0; j < PPT; ++j) {
        int i = base + j;
        float x = P[i * 3], y = P[i * 3 + 1], z = P[i * 3 + 2];
        rx[j] = x; ry[j] = y; rz[j] = z; dmin[j] = 1e30f;
        s_px[i] = x; s_py[i] = y; s_pz[i] = z;
    }
    float lx = P[0], ly = P[1], lz = P[2];
    if (t == 0) s_qi[0] = 0;

    for (int step = 1; step < m; ++step) {
        float bv = -1.0f; int bj = 0;
#pragma unroll
        for (int j = 0; j < PPT; ++j) {
            float d = d2_rn(rx[j] - lx, ry[j] - ly, rz[j] - lz);
            float dm = fminf(dmin[j], d);
            dmin[j] = dm;
            if (dm > bv) { bv = dm; bj = j; }   // strict >: first (lowest) index
        }
        const int bidx = base + bj;

        float v = bv;
        v = dpp_max_f32<0x111, 0xf>(v);   // row_shr:1
        v = dpp_max_f32<0x112, 0xf>(v);   // row_shr:2
        v = dpp_max_f32<0x114, 0xf>(v);   // row_shr:4
        v = dpp_max_f32<0x118, 0xf>(v);   // row_shr:8
        v = dpp_max_f32<0x142, 0xa>(v);   // row_bcast:15
        v = dpp_max_f32<0x143, 0xc>(v);   // row_bcast:31
        const float mv = __int_as_float(__builtin_amdgcn_readlane(__float_as_int(v), 63));
        unsigned long long mb = __ballot(bv == mv);
        const int wl = __ffsll((long long)mb) - 1;
        const int wbi = __builtin_amdgcn_readlane(bidx, wl);

        const int p = step & 1;
        if (lane == 0) s_slot[p * NW + wave] = make_float2(mv, __int_as_float(wbi));
        __syncthreads();

        float2 sl = s_slot[p * NW + (lane & (NW - 1))];
        float gvt = sl.x;
        gvt = dpp_max_f32<0x111, 0xf>(gvt);
        gvt = dpp_max_f32<0x112, 0xf>(gvt);
        if (NW == 8) gvt = dpp_max_f32<0x114, 0xf>(gvt);
        const float gm = __int_as_float(
            __builtin_amdgcn_readlane(__float_as_int(gvt), NW - 1));
        unsigned long long gb = __ballot((lane < NW) && (sl.x == gm));
        const int gl = __ffsll((long long)gb) - 1;        // lowest slot == lowest index
        const int gi = __builtin_amdgcn_readlane(__float_as_int(sl.y), gl);

        lx = s_px[gi]; ly = s_py[gi]; lz = s_pz[gi];      // broadcast reads
        if (t == 0) s_qi[step] = gi;
    }
    __syncthreads();
    for (int e = t; e < m; e += NT) {
        int gi = s_qi[e];
        size_t o = ((size_t)b * m + e) * 3;
        q[o] = s_px[gi]; q[o + 1] = s_py[gi]; q[o + 2] = s_pz[gi];
    }
}

// ---------------- lin_in role: 2 rows per 256-thread block ------------------
__device__ void lin_role(const float* __restrict__ x, const float* __restrict__ w,
                         const float* __restrict__ bias, float* __restrict__ xb,
                         const int blk) {
    const int t = threadIdx.x;
    const int row = blk * 2 + (t >> 7);
    const int col = t & 127;
    float acc = bias[col];
#pragma unroll
    for (int k = 0; k < 16; ++k) acc = fmaf(x[row * 16 + k], w[k * 128 + col], acc);
    xb[row * 128 + col] = fmaxf(acc, 0.0f);
}

// ---------------- nbr role: radius-ball K=64 -> compacted pair list ---------
template <int CHUNK, int WACT>
__device__ void nbr_role(const float* __restrict__ pts, const float* __restrict__ q,
                         int2* __restrict__ pairs, unsigned* __restrict__ counter,
                         const int n, const int m, const int blk, char* smem) {
    const int w = threadIdx.x >> 6, lane = threadIdx.x & 63;
    if (w >= WACT) return;
    float* D = (float*)smem + w * CHUNK * 64;
    const int c = blk * WACT + w;
    const int b = c / m;
    const float* P = pts + (size_t)b * n * 3;
    const float qx = q[(size_t)c * 3 + 0];
    const float qy = q[(size_t)c * 3 + 1];
    const float qz = q[(size_t)c * 3 + 2];
    for (int s = 0; s < CHUNK; ++s) {
        int i = s * 64 + lane;
        float d2 = d2_rn(P[i * 3] - qx, P[i * 3 + 1] - qy, P[i * 3 + 2] - qz);
        D[i] = (d2 <= 4.0f) ? d2 : 1e30f;   // RADIUS^2 = 4
    }
    int my_g = -1;
    int cnt = 0;
    for (int round = 0; round < 64; ++round) {
        float bv = 3e38f;
        int bi = 0x7fffffff;
        for (int s = 0; s < CHUNK; ++s) {
            int i = s * 64 + lane;
            float v = D[i];
            if (v < bv) { bv = v; bi = i; }   // strict <: lowest-index tie-break
        }
#pragma unroll
        for (int off = 32; off >= 1; off >>= 1) {
            float ov = __shfl_xor(bv, off, 64);
            int   oi = __shfl_xor(bi, off, 64);
            if (ov < bv || (ov == bv && oi < bi)) { bv = ov; bi = oi; }
        }
        if (bv > 1e29f) break;               // only invalid/removed remain (uniform)
        if (round == lane) my_g = bi;
        if (lane == (bi & 63)) D[bi] = 3e38f;
        ++cnt;
    }
    unsigned base = 0;
    if (lane == 0) base = atomicAdd(counter, (unsigned)cnt);
    base = (unsigned)__shfl((int)base, 0, 64);
    if (lane < cnt) pairs[base + lane] = make_int2(c, my_g);
}

// ---------------- SA MLP body over compacted rows ---------------------------
typedef float Row132[132];
__device__ void sa_body(const float* __restrict__ xx, const float* __restrict__ pts,
    const float* __restrict__ q, const int2* __restrict__ pairs,
    const unsigned* __restrict__ vcount,
    const float* __restrict__ w1, const float* __restrict__ b1,
    const float* __restrict__ g1, const float* __restrict__ be1,
    const float* __restrict__ w2, const float* __restrict__ b2,
    const float* __restrict__ g2, const float* __restrict__ be2,
    float* __restrict__ hout, const int lm, const int ln, const int blk, char* smem) {
    Row132* shA = (Row132*)smem;                    // 64 rows: 33792 B
    Row132* shW = (Row132*)(smem + 33792);          // 32 rows: 16896 B
    int* sh_c = (int*)(smem + 50688);
    int* sh_g = sh_c + 64;
    const int t = threadIdx.x;
    const int V = (int)*vcount;
    const int r0 = blk * 64;
    if (r0 >= V) return;
    if (t < 64) {
        int r = r0 + t;
        if (r < V) { int2 p = pairs[r]; sh_c[t] = p.x; sh_g[t] = p.y; }
        else { sh_c[t] = -1; sh_g[t] = 0; }
    }
    __syncthreads();

    for (int e = t; e < 64 * 33; e += 256) {
        int row = e / 33, cid = e - row * 33;
        int c = sh_c[row];
        float4 v = make_float4(0.f, 0.f, 0.f, 0.f);
        if (c >= 0) {
            int g = sh_g[row];
            int b = c >> lm;
            size_t pt = ((size_t)(b << ln) + g);
            if (cid < 32) {
                v = *(const float4*)(xx + (pt << 7) + cid * 4);
            } else {
                const float* P = pts + pt * 3;
                const float* Q = q + (size_t)c * 3;
                v.x = P[0] - Q[0]; v.y = P[1] - Q[1]; v.z = P[2] - Q[2]; v.w = 0.f;
            }
        }
        *(float4*)&shA[row][cid * 4] = v;
    }
    __syncthreads();

    const float invs = 1.0f / sqrtf(1.0f + EPSF);
    const int tr = t >> 4, tc = t & 15;
    const int xrow = t >> 2, xcol = t & 3;
    float acc[32];
#pragma unroll
    for (int i = 0; i < 32; ++i) acc[i] = 0.0f;
    float accx = 0.0f;

    for (int k0 = 0; k0 < 132; k0 += 32) {
        const int kc = (132 - k0 < 32) ? (132 - k0) : 32;
        for (int e = t; e < kc * 132; e += 256) {
            int kk = e / 132, j = e - kk * 132;
            int k = k0 + kk;
            shW[kk][j] = (k < 131 && j < 131) ? w1[k * 131 + j] : 0.0f;
        }
        __syncthreads();
        for (int kk = 0; kk < kc; ++kk) {
            const int k = k0 + kk;
            float a0 = shA[4 * tr + 0][k], a1 = shA[4 * tr + 1][k];
            float a2 = shA[4 * tr + 2][k], a3 = shA[4 * tr + 3][k];
            const float4 w0 = *(const float4*)&shW[kk][8 * tc];
            const float4 w1v = *(const float4*)&shW[kk][8 * tc + 4];
            const float wa[8] = {w0.x, w0.y, w0.z, w0.w, w1v.x, w1v.y, w1v.z, w1v.w};
#pragma unroll
            for (int j = 0; j < 8; ++j) {
                acc[0 * 8 + j] = fmaf(a0, wa[j], acc[0 * 8 + j]);
                acc[1 * 8 + j] = fmaf(a1, wa[j], acc[1 * 8 + j]);
                acc[2 * 8 + j] = fmaf(a2, wa[j], acc[2 * 8 + j]);
                acc[3 * 8 + j] = fmaf(a3, wa[j], acc[3 * 8 + j]);
            }
            accx = fmaf(shA[xrow][k], shW[kk][128 + xcol], accx);
        }
        __syncthreads();
    }
#pragma unroll
    for (int i = 0; i < 4; ++i)
#pragma unroll
        for (int j = 0; j < 8; ++j) {
            int col = 8 * tc + j;
            float z = fmaxf(acc[i * 8 + j] + b1[col], 0.0f);
            shA[4 * tr + i][col] = g1[col] * z * invs + be1[col];
        }
    if (xcol < 3) {
        int col = 128 + xcol;
        float z = fmaxf(accx + b1[col], 0.0f);
        shA[xrow][col] = g1[col] * z * invs + be1[col];
    } else {
        shA[xrow][131] = 0.0f;
    }

#pragma unroll
    for (int i = 0; i < 32; ++i) acc[i] = 0.0f;
    for (int k0 = 0; k0 < 132; k0 += 32) {
        const int kc = (132 - k0 < 32) ? (132 - k0) : 32;
        for (int e = t; e < kc * 132; e += 256) {
            int kk = e / 132, j = e - kk * 132;
            int k = k0 + kk;
            shW[kk][j] = (k < 131 && j < 128) ? w2[k * 128 + j] : 0.0f;
        }
        __syncthreads();
        for (int kk = 0; kk < kc; ++kk) {
            const int k = k0 + kk;
            float a0 = shA[4 * tr + 0][k], a1 = shA[4 * tr + 1][k];
            float a2 = shA[4 * tr + 2][k], a3 = shA[4 * tr + 3][k];
            const float4 w0 = *(const float4*)&shW[kk][8 * tc];
            const float4 w1v = *(const float4*)&shW[kk][8 * tc + 4];
            const float wa[8] = {w0.x, w0.y, w0.z, w0.w, w1v.x, w1v.y, w1v.z, w1v.w};
#pragma unroll
            for (int j = 0; j < 8; ++j) {
                acc[0 * 8 + j] = fmaf(a0, wa[j], acc[0 * 8 + j]);
                acc[1 * 8 + j] = fmaf(a1, wa[j], acc[1 * 8 + j]);
                acc[2 * 8 + j] = fmaf(a2, wa[j], acc[2 * 8 + j]);
                acc[3 * 8 + j] = fmaf(a3, wa[j], acc[3 * 8 + j]);
            }
        }
        __syncthreads();
    }
#pragma unroll
    for (int i = 0; i < 4; ++i)
#pragma unroll
        for (int j = 0; j < 8; ++j) {
            int col = 8 * tc + j;
            float z = fmaxf(acc[i * 8 + j] + b2[col], 0.0f);
            shA[4 * tr + i][col] = g2[col] * z * invs + be2[col];
        }
    __syncthreads();

    if (t < 128) {
        const int col = t;
        float run = -1.0f;
        int cur = sh_c[0];
        for (int row = 0; row < 64; ++row) {
            int c = sh_c[row];
            if (c != cur) {
                if (cur >= 0)
                    atomicMax((unsigned*)&hout[((size_t)cur << 7) + col], __float_as_uint(run));
                run = -1.0f; cur = c;
            }
            run = fmaxf(run, shA[row][col]);
        }
        if (cur >= 0)
            atomicMax((unsigned*)&hout[((size_t)cur << 7) + col], __float_as_uint(run));
    }
}

// ---------------- knn role: 3-NN search + inverse-d2 weights ----------------
__device__ void knn_role(const float* __restrict__ pf, const float* __restrict__ pc,
                         int* __restrict__ kidx, float* __restrict__ kw,
                         const int nf, const int nc, const int blk) {
    const int tg = blk * 256 + threadIdx.x;
    const int b = tg / nf;
    const float* F = pf + (size_t)tg * 3;
    const float fx = F[0], fy = F[1], fz = F[2];
    const float* C = pc + (size_t)b * nc * 3;
    float b0 = 1e30f, b1 = 1e30f, b2 = 1e30f;
    int i0 = 0, i1 = 0, i2 = 0;
    for (int j = 0; j < nc; ++j) {
        float d2 = d2_rn(C[j * 3] - fx, C[j * 3 + 1] - fy, C[j * 3 + 2] - fz);
        if (d2 < b0)      { b2 = b1; i2 = i1; b1 = b0; i1 = i0; b0 = d2; i0 = j; }
        else if (d2 < b1) { b2 = b1; i2 = i1; b1 = d2; i1 = j; }
        else if (d2 < b2) { b2 = d2; i2 = j; }
    }
    float w0 = 1.0f / fmaxf(b0, 1e-16f);
    float w1 = 1.0f / fmaxf(b1, 1e-16f);
    float w2 = 1.0f / fmaxf(b2, 1e-16f);
    float inv = 1.0f / (w0 + w1 + w2);
    size_t o = (size_t)tg * 3;
    kidx[o] = i0; kidx[o + 1] = i1; kidx[o + 2] = i2;
    kw[o] = w0 * inv; kw[o + 1] = w1 * inv; kw[o + 2] = w2 * inv;
}

// ---------------- stage kernels --------------------------------------------
// stage A: fps0 (blocks 0..3) || lin_in (8192) || zero h-bufs + ctrs (1792)
__global__ __launch_bounds__(256) void stage_a_kernel(
    const float* __restrict__ pos, float* __restrict__ q1,
    const float* __restrict__ x, const float* __restrict__ lin_w,
    const float* __restrict__ lin_b, float* __restrict__ xb,
    float* __restrict__ hbuf, unsigned* __restrict__ ctrs) {
    __shared__ __align__(16) char smem[57408];
    const int blk = blockIdx.x;
    if (blk < 4) {
        fps_role<4096, 256>(pos, q1, 2048, blk, smem);
    } else if (blk < 4 + 8192) {
        lin_role(x, lin_w, lin_b, xb, blk - 4);
    } else {
        const int i = blk - 8196;
        *(float4*)(hbuf + (size_t)i * 1024 + threadIdx.x * 4) =
            make_float4(0.f, 0.f, 0.f, 0.f);
        if (i == 0 && threadIdx.x < 3) ctrs[threadIdx.x * 16] = 0u;
    }
}

// stage B: fps1 (0..3) || nbr level-0 (4096 blocks, 2 active waves each)
__global__ __launch_bounds__(256) void stage_b_kernel(
    const float* __restrict__ q1, float* __restrict__ q2,
    const float* __restrict__ pos, int2* __restrict__ pairs1,
    unsigned* __restrict__ ctr0) {
    __shared__ __align__(16) char smem[32768];
    const int blk = blockIdx.x;
    if (blk < 4) fps_role<2048, 256>(q1, q2, 1024, blk, smem);
    else nbr_role<64, 2>(pos, q1, pairs1, ctr0, 4096, 2048, blk - 4, smem);
}

// stage C: fps2 (0..3) || nbr level-1 (1024) || sa level-0 (8192)
__global__ __launch_bounds__(256) void stage_c_kernel(
    const float* __restrict__ q2, float* __restrict__ q3,
    const float* __restrict__ q1, int2* __restrict__ pairs2,
    unsigned* __restrict__ ctr1,
    const float* __restrict__ xb, const float* __restrict__ pos,
    const int2* __restrict__ pairs1, const unsigned* __restrict__ ctr0,
    const float* __restrict__ w1, const float* __restrict__ b1,
    const float* __restrict__ g1, const float* __restrict__ be1,
    const float* __restrict__ w2, const float* __restrict__ b2,
    const float* __restrict__ g2, const float* __restrict__ be2,
    float* __restrict__ h1) {
    __shared__ __align__(16) char smem[51200];
    const int blk = blockIdx.x;
    if (blk < 4) fps_role<1024, 256>(q2, q3, 512, blk, smem);
    else if (blk < 4 + 1024)
        nbr_role<32, 4>(q1, q2, pairs2, ctr1, 2048, 1024, blk - 4, smem);
    else
        sa_body(xb, pos, q1, pairs1, ctr0, w1, b1, g1, be1, w2, b2, g2, be2,
                h1, 11, 12, blk - 1028, smem);
}

// stage D: nbr level-2 (512) || knn step-0 (16) || sa level-1 (4096)
__global__ __launch_bounds__(256) void stage_d_kernel(
    const float* __restrict__ q2, const float* __restrict__ q3,
    int2* __restrict__ pairs3, unsigned* __restrict__ ctr2,
    const float* __restrict__ h1, const float* __restrict__ q1,
    const int2* __restrict__ pairs2, const unsigned* __restrict__ ctr1,
    const float* __restrict__ w1, const float* __restrict__ b1,
    const float* __restrict__ g1, const float* __restrict__ be1,
    const float* __restrict__ w2, const float* __restrict__ b2,
    const float* __restrict__ g2, const float* __restrict__ be2,
    float* __restrict__ h2, int* __restrict__ kidx, float* __restrict__ kw) {
    __shared__ __align__(16) char smem[51200];
    const int blk = blockIdx.x;
    if (blk < 512) nbr_role<16, 4>(q2, q3, pairs3, ctr2, 1024, 512, blk, smem);
    else if (blk < 512 + 16) knn_role(q2, q3, kidx, kw, 1024, 512, blk - 512);
    else
        sa_body(h1, q1, q2, pairs2, ctr1, w1, b1, g1, be1, w2, b2, g2, be2,
                h2, 10, 11, blk - 528, smem);
}

// ---------------- standalone wrappers (sa level-2, knn steps 1/2) -----------
__global__ __launch_bounds__(256) void sa_fused_kernel(
    const float* xx, const float* pts, const float* q, const int2* pairs,
    const unsigned* vcount,
    const float* w1, const float* b1, const float* g1, const float* be1,
    const float* w2, const float* b2, const float* g2, const float* be2,
    float* hout, int lm, int ln) {
    __shared__ __align__(16) char smem[51200];
    sa_body(xx, pts, q, pairs, vcount, w1, b1, g1, be1, w2, b2, g2, be2,
            hout, lm, ln, blockIdx.x, smem);
}

__global__ __launch_bounds__(256) void knn_kernel(
    const float* pf, const float* pc, int* kidx, float* kw, int nf, int nc) {
    knn_role(pf, pc, kidx, kw, nf, nc, blockIdx.x);
}

// ---------------- interpolate + concat skip -> cat[f][256] ------------------
__global__ __launch_bounds__(256) void interp_cat_kernel(
    const float* __restrict__ xc, const float* __restrict__ xs,
    const int* __restrict__ kidx, const float* __restrict__ kw,
    float* __restrict__ cat, int nf, int nc) {
    const int f = blockIdx.x;
    const int t = threadIdx.x;
    const int b = f / nf;
    const size_t o = (size_t)f * 3;
    if (t < 128) {
        int i0 = kidx[o], i1 = kidx[o + 1], i2 = kidx[o + 2];
        float w0 = kw[o], w1 = kw[o + 1], w2 = kw[o + 2];
        const float* X = xc + (size_t)b * nc * 128;
        float y = w0 * X[(size_t)i0 * 128 + t] + w1 * X[(size_t)i1 * 128 + t] +
                  w2 * X[(size_t)i2 * 128 + t];
        cat[(size_t)f * 256 + t] = y;
    } else {
        cat[(size_t)f * 256 + t] = xs[(size_t)f * 128 + (t - 128)];
    }
}

// ---------------- generic GEMM + bias + relu + BN epilogue ------------------
__global__ __launch_bounds__(256) void gemm_bn_kernel(
    const float* __restrict__ A, const float* __restrict__ W,
    const float* __restrict__ bias, const float* __restrict__ g,
    const float* __restrict__ be, float* __restrict__ C, int Kin, int Cout) {
    __shared__ __align__(16) float shA[64][33];
    __shared__ __align__(16) float shB[32][68];
    const int t = threadIdx.x;
    const int r0 = blockIdx.x * 64;
    const int c0 = blockIdx.y * 64;
    const int tr = t >> 4, tc = t & 15;
    const float invs = 1.0f / sqrtf(1.0f + EPSF);
    float acc[16];
#pragma unroll
    for (int i = 0; i < 16; ++i) acc[i] = 0.0f;
    for (int k0 = 0; k0 < Kin; k0 += 32) {
#pragma unroll
        for (int e = t; e < 2048; e += 256) {
            int r = e >> 5, kk = e & 31;
            shA[r][kk] = A[(size_t)(r0 + r) * Kin + k0 + kk];
        }
#pragma unroll
        for (int e = t; e < 2048; e += 256) {
            int kk = e >> 6, cc = e & 63;
            shB[kk][cc] = W[(size_t)(k0 + kk) * Cout + c0 + cc];
        }
        __syncthreads();
        for (int kk = 0; kk < 32; ++kk) {
            float av[4];
#pragma unroll
            for (int i = 0; i < 4; ++i) av[i] = shA[4 * tr + i][kk];
            const float4 wv = *(const float4*)&shB[kk][4 * tc];
            const float wa[4] = {wv.x, wv.y, wv.z, wv.w};
#pragma unroll
            for (int i = 0; i < 4; ++i)
#pragma unroll
                for (int jj = 0; jj < 4; ++jj)
                    acc[i * 4 + jj] = fmaf(av[i], wa[jj], acc[i * 4 + jj]);
        }
        __syncthreads();
    }
#pragma unroll
    for (int i = 0; i < 4; ++i)
#pragma unroll
        for (int jj = 0; jj < 4; ++jj) {
            int col = c0 + 4 * tc + jj;
            float z = fmaxf(acc[i * 4 + jj] + bias[col], 0.0f);
            C[(size_t)(r0 + 4 * tr + i) * Cout + col] = g[col] * z * invs + be[col];
        }
}

// ---------------- final 128 -> 2 layer --------------------------------------
__global__ __launch_bounds__(256) void lo2_kernel(
    const float* __restrict__ in, const float* __restrict__ w,
    const float* __restrict__ b, const float* __restrict__ g,
    const float* __restrict__ be, float* __restrict__ out) {
    __shared__ float sw[256];
    const int t = threadIdx.x;
    sw[t] = w[t];
    __syncthreads();
    const int row = blockIdx.x * 256 + t;
    const float invs = 1.0f / sqrtf(1.0f + EPSF);
    float a0 = b[0], a1 = b[1];
    const float* R = in + (size_t)row * 128;
    for (int k = 0; k < 128; ++k) {
        float a = R[k];
        a0 = fmaf(a, sw[k * 2], a0);
        a1 = fmaf(a, sw[k * 2 + 1], a1);
    }
    a0 = fmaxf(a0, 0.0f);
    a1 = fmaxf(a1, 0.0f);
    out[(size_t)row * 2]     = g[0] * a0 * invs + be[0];
    out[(size_t)row * 2 + 1] = g[1] * a1 * invs + be[1];
}

// ---------------------------------------------------------------------------
extern "C" void kernel_launch(void* const* d_in, const int* in_sizes, int n_in,
                              void* d_out, int out_size, void* d_ws, size_t ws_size,
                              hipStream_t stream) {
    const float* x      = (const float*)d_in[0];
    const float* pos    = (const float*)d_in[1];
    const float* lin_w  = (const float*)d_in[3];
    const float* lin_b  = (const float*)d_in[4];
    const float* sa_w1  = (const float*)d_in[5];
    const float* sa_b1  = (const float*)d_in[6];
    const float* sa_g1  = (const float*)d_in[7];
    const float* sa_be1 = (const float*)d_in[8];
    const float* sa_w2  = (const float*)d_in[9];
    const float* sa_b2  = (const float*)d_in[10];
    const float* sa_g2  = (const float*)d_in[11];
    const float* sa_be2 = (const float*)d_in[12];
    const float* fp_w1  = (const float*)d_in[13];
    const float* fp_b1  = (const float*)d_in[14];
    const float* fp_g1  = (const float*)d_in[15];
    const float* fp_be1 = (const float*)d_in[16];
    const float* fp_w2  = (const float*)d_in[17];
    const float* fp_b2  = (const float*)d_in[18];
    const float* fp_g2  = (const float*)d_in[19];
    const float* fp_be2 = (const float*)d_in[20];
    const float* lo_w1  = (const float*)d_in[21];
    const float* lo_b1  = (const float*)d_in[22];
    const float* lo_g1  = (const float*)d_in[23];
    const float* lo_be1 = (const float*)d_in[24];
    const float* lo_w2  = (const float*)d_in[25];
    const float* lo_b2  = (const float*)d_in[26];
    const float* lo_g2  = (const float*)d_in[27];
    const float* lo_be2 = (const float*)d_in[28];

    float* ws = (float*)d_ws;
    size_t off = 0;
    auto alloc = [&](size_t n) { float* p = ws + off; off += n; return p; };
    float* xb    = alloc(4 * 4096 * 128);
    float* q1    = alloc(4 * 2048 * 3);
    float* q2    = alloc(4 * 1024 * 3);
    float* q3    = alloc(4 * 512 * 3);
    float* h1    = alloc(4 * 2048 * 128);   // h1,h2,h3 contiguous for zero role
    float* h2    = alloc(4 * 1024 * 128);
    float* h3    = alloc(4 * 512 * 128);
    int2* pairs1 = (int2*)alloc(4 * 2048 * 64 * 2);
    int2* pairs2 = (int2*)alloc(4 * 1024 * 64 * 2);
    int2* pairs3 = (int2*)alloc(4 * 512 * 64 * 2);
    unsigned* ctrs = (unsigned*)alloc(64);   // [0],[16],[32] per level
    int* kidx    = (int*)alloc(4 * 4096 * 3);
    float* kw    = alloc(4 * 4096 * 3);
    float* cat   = alloc(4 * 4096 * 256);
    float* mbuf  = alloc(4 * 4096 * 256);
    float* xfA   = alloc(4 * 4096 * 128);
    float* xfB   = alloc(4 * 4096 * 128);
    if (ws_size < off * sizeof(float)) return;

    // stage A: fps0 || lin_in || zero (h1|h2|h3 = 4*3584*128 = 1792*1024 floats)
    stage_a_kernel<<<4 + 8192 + 1792, 256, 0, stream>>>(
        pos, q1, x, lin_w, lin_b, xb, h1, ctrs);

    // stage B: fps1 || nbr0
    stage_b_kernel<<<4 + 4096, 256, 0, stream>>>(q1, q2, pos, pairs1, ctrs + 0);

    // stage C: fps2 || nbr1 || sa0
    stage_c_kernel<<<4 + 1024 + 8192, 256, 0, stream>>>(
        q2, q3, q1, pairs2, ctrs + 16,
        xb, pos, pairs1, ctrs + 0,
        sa_w1, sa_b1, sa_g1, sa_be1, sa_w2, sa_b2, sa_g2, sa_be2, h1);

    // stage D: nbr2 || knn0 || sa1
    stage_d_kernel<<<512 + 16 + 4096, 256, 0, stream>>>(
        q2, q3, pairs3, ctrs + 32,
        h1, q1, pairs2, ctrs + 16,
        sa_w1 + 131 * 131, sa_b1 + 131, sa_g1 + 131, sa_be1 + 131,
        sa_w2 + 131 * 128, sa_b2 + 128, sa_g2 + 128, sa_be2 + 128, h2,
        kidx, kw);

    // sa level 2
    sa_fused_kernel<<<2048, 256, 0, stream>>>(h2, q2, q3, pairs3, ctrs + 32,
        sa_w1 + 2 * 131 * 131, sa_b1 + 2 * 131, sa_g1 + 2 * 131, sa_be1 + 2 * 131,
        sa_w2 + 2 * 131 * 128, sa_b2 + 2 * 128, sa_g2 + 2 * 128, sa_be2 + 2 * 128,
        h3, 9, 10);

    // ---- FP step 0 (mi=2): 512 -> 1024 (knn0 already done in stage D) ----
    interp_cat_kernel<<<4 * 1024, 256, 0, stream>>>(h3, h2, kidx, kw, cat, 1024, 512);
    gemm_bn_kernel<<<dim3(4096 / 64, 4), 256, 0, stream>>>(cat,
        fp_w1 + 2 * 256 * 256, fp_b1 + 2 * 256, fp_g1 + 2 * 256, fp_be1 + 2 * 256,
        mbuf, 256, 256);
    gemm_bn_kernel<<<dim3(4096 / 64, 2), 256, 0, stream>>>(mbuf,
        fp_w2 + 2 * 256 * 128, fp_b2 + 2 * 128, fp_g2 + 2 * 128, fp_be2 + 2 * 128,
        xfA, 256, 128);

    // ---- FP step 1 (mi=1): 1024 -> 2048 ----
    knn_kernel<<<(4 * 2048) / 256, 256, 0, stream>>>(q1, q2, kidx, kw, 2048, 1024);
    interp_cat_kernel<<<4 * 2048, 256, 0, stream>>>(xfA, h1, kidx, kw, cat, 2048, 1024);
    gemm_bn_kernel<<<dim3(8192 / 64, 4), 256, 0, stream>>>(cat,
        fp_w1 + 256 * 256, fp_b1 + 256, fp_g1 + 256, fp_be1 + 256,
        mbuf, 256, 256);
    gemm_bn_kernel<<<dim3(8192 / 64, 2), 256, 0, stream>>>(mbuf,
        fp_w2 + 256 * 128, fp_b2 + 128, fp_g2 + 128, fp_be2 + 128,
        xfB, 256, 128);

    // ---- FP step 2 (mi=0): 2048 -> 4096 ----
    knn_kernel<<<(4 * 4096) / 256, 256, 0, stream>>>(pos, q1, kidx, kw, 4096, 2048);
    interp_cat_kernel<<<4 * 4096, 256, 0, stream>>>(xfB, xb, kidx, kw, cat, 4096, 2048);
    gemm_bn_kernel<<<dim3(16384 / 64, 4), 256, 0, stream>>>(cat,
        fp_w1, fp_b1, fp_g1, fp_be1, mbuf, 256, 256);
    gemm_bn_kernel<<<dim3(16384 / 64, 2), 256, 0, stream>>>(mbuf,
        fp_w2, fp_b2, fp_g2, fp_be2, xfA, 256, 128);

    // ---- output MLP ----
    gemm_bn_kernel<<<dim3(16384 / 64, 2), 256, 0, stream>>>(xfA,
        lo_w1, lo_b1, lo_g1, lo_be1, mbuf, 128, 128);
    lo2_kernel<<<16384 / 256, 256, 0, stream>>>(mbuf, lo_w2, lo_b2, lo_g2, lo_be2,
        (float*)d_out);
}

// Round 10
// 3519.621 us; speedup vs baseline: 1.3117x; 1.0882x over previous
//
#include <hip/hip_runtime.h>
#include <cstddef>

// ---------------------------------------------------------------------------
// PointNet++ (B=4, N0=4096, NIN=16, NH=128, NOUT=2, DEPTH=3, K=64, R=2, KNN=3)
// fp32. Selection paths (FPS argmax, radius top-K, 3-NN) use non-contracted
// fp32 ops + first-index tie-breaks to match the reference bit-for-bit.
// FPS math = round-7 proven structure, unchanged. Stage kernels overlap the
// serial FPS chain with nbr/sa/knn work of the previous level.
// NEW (round 10): each FP step (knn-interp + concat + 256->256 + 256->128)
// is ONE kernel: A-tile gathered/interpolated straight into LDS, H1
// overwrites the A buffer, weights streamed in 16-row panels. knn searches
// hoisted into stages b/c/d (coordinate-only dependencies).
// ---------------------------------------------------------------------------

#define EPSF 1e-5f

__device__ __forceinline__ float d2_rn(float dx, float dy, float dz) {
    return __fadd_rn(__fadd_rn(__fmul_rn(dx, dx), __fmul_rn(dy, dy)), __fmul_rn(dz, dz));
}

template <int CTRL, int RMASK>
__device__ __forceinline__ float dpp_max_f32(float v) {
    int o = __builtin_amdgcn_update_dpp(__float_as_int(v), __float_as_int(v),
                                        CTRL, RMASK, 0xf, false);
    return fmaxf(v, __int_as_float(o));
}

// ---------------- FPS role (round-7 math verbatim; LDS via pointer) ---------
template <int N, int NT>
__device__ void fps_role(const float* __restrict__ pts, float* __restrict__ q,
                         const int m, const int b, char* smem) {
    constexpr int PPT = N / NT;
    constexpr int NW = NT / 64;
    float* s_px = (float*)smem;
    float* s_py = s_px + N;
    float* s_pz = s_py + N;
    int*   s_qi = (int*)(s_pz + N);
    float2* s_slot = (float2*)(s_qi + N / 2);   // [2][NW]
    const int t = threadIdx.x;
    const int wave = t >> 6, lane = t & 63;
    const int base = t * PPT;                    // blocked assignment
    const float* P = pts + (size_t)b * N * 3;
    asm volatile("s_setprio 3");                 // protect serial chain
    float rx[PPT], ry[PPT], rz[PPT], dmin[PPT];
#pragma unroll
    for (int j = 0; j < PPT; ++j) {
        int i = base + j;
        float x = P[i * 3], y = P[i * 3 + 1], z = P[i * 3 + 2];
        rx[j] = x; ry[j] = y; rz[j] = z; dmin[j] = 1e30f;
        s_px[i] = x; s_py[i] = y; s_pz[i] = z;
    }
    float lx = P[0], ly = P[1], lz = P[2];
    if (t == 0) s_qi[0] = 0;

    for (int step = 1; step < m; ++step) {
        float bv = -1.0f; int bj = 0;
#pragma unroll
        for (int j = 0; j < PPT; ++j) {
            float d = d2_rn(rx[j] - lx, ry[j] - ly, rz[j] - lz);
            float dm = fminf(dmin[j], d);
            dmin[j] = dm;
            if (dm > bv) { bv = dm; bj = j; }   // strict >: first (lowest) index
        }
        const int bidx = base + bj;

        float v = bv;
        v = dpp_max_f32<0x111, 0xf>(v);   // row_shr:1
        v = dpp_max_f32<0x112, 0xf>(v);   // row_shr:2
        v = dpp_max_f32<0x114, 0xf>(v);   // row_shr:4
        v = dpp_max_f32<0x118, 0xf>(v);   // row_shr:8
        v = dpp_max_f32<0x142, 0xa>(v);   // row_bcast:15
        v = dpp_max_f32<0x143, 0xc>(v);   // row_bcast:31
        const float mv = __int_as_float(__builtin_amdgcn_readlane(__float_as_int(v), 63));
        unsigned long long mb = __ballot(bv == mv);
        const int wl = __ffsll((long long)mb) - 1;
        const int wbi = __builtin_amdgcn_readlane(bidx, wl);

        const int p = step & 1;
        if (lane == 0) s_slot[p * NW + wave] = make_float2(mv, __int_as_float(wbi));
        __syncthreads();

        float2 sl = s_slot[p * NW + (lane & (NW - 1))];
        float gvt = sl.x;
        gvt = dpp_max_f32<0x111, 0xf>(gvt);
        gvt = dpp_max_f32<0x112, 0xf>(gvt);
        if (NW == 8) gvt = dpp_max_f32<0x114, 0xf>(gvt);
        const float gm = __int_as_float(
            __builtin_amdgcn_readlane(__float_as_int(gvt), NW - 1));
        unsigned long long gb = __ballot((lane < NW) && (sl.x == gm));
        const int gl = __ffsll((long long)gb) - 1;        // lowest slot == lowest index
        const int gi = __builtin_amdgcn_readlane(__float_as_int(sl.y), gl);

        lx = s_px[gi]; ly = s_py[gi]; lz = s_pz[gi];      // broadcast reads
        if (t == 0) s_qi[step] = gi;
    }
    __syncthreads();
    for (int e = t; e < m; e += NT) {
        int gi = s_qi[e];
        size_t o = ((size_t)b * m + e) * 3;
        q[o] = s_px[gi]; q[o + 1] = s_py[gi]; q[o + 2] = s_pz[gi];
    }
}

// ---------------- lin_in role: 2 rows per 256-thread block ------------------
__device__ void lin_role(const float* __restrict__ x, const float* __restrict__ w,
                         const float* __restrict__ bias, float* __restrict__ xb,
                         const int blk) {
    const int t = threadIdx.x;
    const int row = blk * 2 + (t >> 7);
    const int col = t & 127;
    float acc = bias[col];
#pragma unroll
    for (int k = 0; k < 16; ++k) acc = fmaf(x[row * 16 + k], w[k * 128 + col], acc);
    xb[row * 128 + col] = fmaxf(acc, 0.0f);
}

// ---------------- nbr role: radius-ball K=64 -> compacted pair list ---------
template <int CHUNK, int WACT>
__device__ void nbr_role(const float* __restrict__ pts, const float* __restrict__ q,
                         int2* __restrict__ pairs, unsigned* __restrict__ counter,
                         const int n, const int m, const int blk, char* smem) {
    const int w = threadIdx.x >> 6, lane = threadIdx.x & 63;
    if (w >= WACT) return;
    float* D = (float*)smem + w * CHUNK * 64;
    const int c = blk * WACT + w;
    const int b = c / m;
    const float* P = pts + (size_t)b * n * 3;
    const float qx = q[(size_t)c * 3 + 0];
    const float qy = q[(size_t)c * 3 + 1];
    const float qz = q[(size_t)c * 3 + 2];
    for (int s = 0; s < CHUNK; ++s) {
        int i = s * 64 + lane;
        float d2 = d2_rn(P[i * 3] - qx, P[i * 3 + 1] - qy, P[i * 3 + 2] - qz);
        D[i] = (d2 <= 4.0f) ? d2 : 1e30f;   // RADIUS^2 = 4
    }
    int my_g = -1;
    int cnt = 0;
    for (int round = 0; round < 64; ++round) {
        float bv = 3e38f;
        int bi = 0x7fffffff;
        for (int s = 0; s < CHUNK; ++s) {
            int i = s * 64 + lane;
            float v = D[i];
            if (v < bv) { bv = v; bi = i; }   // strict <: lowest-index tie-break
        }
#pragma unroll
        for (int off = 32; off >= 1; off >>= 1) {
            float ov = __shfl_xor(bv, off, 64);
            int   oi = __shfl_xor(bi, off, 64);
            if (ov < bv || (ov == bv && oi < bi)) { bv = ov; bi = oi; }
        }
        if (bv > 1e29f) break;               // only invalid/removed remain (uniform)
        if (round == lane) my_g = bi;
        if (lane == (bi & 63)) D[bi] = 3e38f;
        ++cnt;
    }
    unsigned base = 0;
    if (lane == 0) base = atomicAdd(counter, (unsigned)cnt);
    base = (unsigned)__shfl((int)base, 0, 64);
    if (lane < cnt) pairs[base + lane] = make_int2(c, my_g);
}

// ---------------- SA MLP body over compacted rows ---------------------------
typedef float Row132[132];
__device__ void sa_body(const float* __restrict__ xx, const float* __restrict__ pts,
    const float* __restrict__ q, const int2* __restrict__ pairs,
    const unsigned* __restrict__ vcount,
    const float* __restrict__ w1, const float* __restrict__ b1,
    const float* __restrict__ g1, const float* __restrict__ be1,
    const float* __restrict__ w2, const float* __restrict__ b2,
    const float* __restrict__ g2, const float* __restrict__ be2,
    float* __restrict__ hout, const int lm, const int ln, const int blk, char* smem) {
    Row132* shA = (Row132*)smem;                    // 64 rows: 33792 B
    Row132* shW = (Row132*)(smem + 33792);          // 32 rows: 16896 B
    int* sh_c = (int*)(smem + 50688);
    int* sh_g = sh_c + 64;
    const int t = threadIdx.x;
    const int V = (int)*vcount;
    const int r0 = blk * 64;
    if (r0 >= V) return;
    if (t < 64) {
        int r = r0 + t;
        if (r < V) { int2 p = pairs[r]; sh_c[t] = p.x; sh_g[t] = p.y; }
        else { sh_c[t] = -1; sh_g[t] = 0; }
    }
    __syncthreads();

    for (int e = t; e < 64 * 33; e += 256) {
        int row = e / 33, cid = e - row * 33;
        int c = sh_c[row];
        float4 v = make_float4(0.f, 0.f, 0.f, 0.f);
        if (c >= 0) {
            int g = sh_g[row];
            int b = c >> lm;
            size_t pt = ((size_t)(b << ln) + g);
            if (cid < 32) {
                v = *(const float4*)(xx + (pt << 7) + cid * 4);
            } else {
                const float* P = pts + pt * 3;
                const float* Q = q + (size_t)c * 3;
                v.x = P[0] - Q[0]; v.y = P[1] - Q[1]; v.z = P[2] - Q[2]; v.w = 0.f;
            }
        }
        *(float4*)&shA[row][cid * 4] = v;
    }
    __syncthreads();

    const float invs = 1.0f / sqrtf(1.0f + EPSF);
    const int tr = t >> 4, tc = t & 15;
    const int xrow = t >> 2, xcol = t & 3;
    float acc[32];
#pragma unroll
    for (int i = 0; i < 32; ++i) acc[i] = 0.0f;
    float accx = 0.0f;

    for (int k0 = 0; k0 < 132; k0 += 32) {
        const int kc = (132 - k0 < 32) ? (132 - k0) : 32;
        for (int e = t; e < kc * 132; e += 256) {
            int kk = e / 132, j = e - kk * 132;
            int k = k0 + kk;
            shW[kk][j] = (k < 131 && j < 131) ? w1[k * 131 + j] : 0.0f;
        }
        __syncthreads();
        for (int kk = 0; kk < kc; ++kk) {
            const int k = k0 + kk;
            float a0 = shA[4 * tr + 0][k], a1 = shA[4 * tr + 1][k];
            float a2 = shA[4 * tr + 2][k], a3 = shA[4 * tr + 3][k];
            const float4 w0 = *(const float4*)&shW[kk][8 * tc];
            const float4 w1v = *(const float4*)&shW[kk][8 * tc + 4];
            const float wa[8] = {w0.x, w0.y, w0.z, w0.w, w1v.x, w1v.y, w1v.z, w1v.w};
#pragma unroll
            for (int j = 0; j < 8; ++j) {
                acc[0 * 8 + j] = fmaf(a0, wa[j], acc[0 * 8 + j]);
                acc[1 * 8 + j] = fmaf(a1, wa[j], acc[1 * 8 + j]);
                acc[2 * 8 + j] = fmaf(a2, wa[j], acc[2 * 8 + j]);
                acc[3 * 8 + j] = fmaf(a3, wa[j], acc[3 * 8 + j]);
            }
            accx = fmaf(shA[xrow][k], shW[kk][128 + xcol], accx);
        }
        __syncthreads();
    }
#pragma unroll
    for (int i = 0; i < 4; ++i)
#pragma unroll
        for (int j = 0; j < 8; ++j) {
            int col = 8 * tc + j;
            float z = fmaxf(acc[i * 8 + j] + b1[col], 0.0f);
            shA[4 * tr + i][col] = g1[col] * z * invs + be1[col];
        }
    if (xcol < 3) {
        int col = 128 + xcol;
        float z = fmaxf(accx + b1[col], 0.0f);
        shA[xrow][col] = g1[col] * z * invs + be1[col];
    } else {
        shA[xrow][131] = 0.0f;
    }

#pragma unroll
    for (int i = 0; i < 32; ++i) acc[i] = 0.0f;
    for (int k0 = 0; k0 < 132; k0 += 32) {
        const int kc = (132 - k0 < 32) ? (132 - k0) : 32;
        for (int e = t; e < kc * 132; e += 256) {
            int kk = e / 132, j = e - kk * 132;
            int k = k0 + kk;
            shW[kk][j] = (k < 131 && j < 128) ? w2[k * 128 + j] : 0.0f;
        }
        __syncthreads();
        for (int kk = 0; kk < kc; ++kk) {
            const int k = k0 + kk;
            float a0 = shA[4 * tr + 0][k], a1 = shA[4 * tr + 1][k];
            float a2 = shA[4 * tr + 2][k], a3 = shA[4 * tr + 3][k];
            const float4 w0 = *(const float4*)&shW[kk][8 * tc];
            const float4 w1v = *(const float4*)&shW[kk][8 * tc + 4];
            const float wa[8] = {w0.x, w0.y, w0.z, w0.w, w1v.x, w1v.y, w1v.z, w1v.w};
#pragma unroll
            for (int j = 0; j < 8; ++j) {
                acc[0 * 8 + j] = fmaf(a0, wa[j], acc[0 * 8 + j]);
                acc[1 * 8 + j] = fmaf(a1, wa[j], acc[1 * 8 + j]);
                acc[2 * 8 + j] = fmaf(a2, wa[j], acc[2 * 8 + j]);
                acc[3 * 8 + j] = fmaf(a3, wa[j], acc[3 * 8 + j]);
            }
        }
        __syncthreads();
    }
#pragma unroll
    for (int i = 0; i < 4; ++i)
#pragma unroll
        for (int j = 0; j < 8; ++j) {
            int col = 8 * tc + j;
            float z = fmaxf(acc[i * 8 + j] + b2[col], 0.0f);
            shA[4 * tr + i][col] = g2[col] * z * invs + be2[col];
        }
    __syncthreads();

    if (t < 128) {
        const int col = t;
        float run = -1.0f;
        int cur = sh_c[0];
        for (int row = 0; row < 64; ++row) {
            int c = sh_c[row];
            if (c != cur) {
                if (cur >= 0)
                    atomicMax((unsigned*)&hout[((size_t)cur << 7) + col], __float_as_uint(run));
                run = -1.0f; cur = c;
            }
            run = fmaxf(run, shA[row][col]);
        }
        if (cur >= 0)
            atomicMax((unsigned*)&hout[((size_t)cur << 7) + col], __float_as_uint(run));
    }
}

// ---------------- knn role: 3-NN search + inverse-d2 weights ----------------
__device__ void knn_role(const float* __restrict__ pf, const float* __restrict__ pc,
                         int* __restrict__ kidx, float* __restrict__ kw,
                         const int nf, const int nc, const int blk) {
    const int tg = blk * 256 + threadIdx.x;
    const int b = tg / nf;
    const float* F = pf + (size_t)tg * 3;
    const float fx = F[0], fy = F[1], fz = F[2];
    const float* C = pc + (size_t)b * nc * 3;
    float b0 = 1e30f, b1 = 1e30f, b2 = 1e30f;
    int i0 = 0, i1 = 0, i2 = 0;
    for (int j = 0; j < nc; ++j) {
        float d2 = d2_rn(C[j * 3] - fx, C[j * 3 + 1] - fy, C[j * 3 + 2] - fz);
        if (d2 < b0)      { b2 = b1; i2 = i1; b1 = b0; i1 = i0; b0 = d2; i0 = j; }
        else if (d2 < b1) { b2 = b1; i2 = i1; b1 = d2; i1 = j; }
        else if (d2 < b2) { b2 = d2; i2 = j; }
    }
    float w0 = 1.0f / fmaxf(b0, 1e-16f);
    float w1 = 1.0f / fmaxf(b1, 1e-16f);
    float w2 = 1.0f / fmaxf(b2, 1e-16f);
    float inv = 1.0f / (w0 + w1 + w2);
    size_t o = (size_t)tg * 3;
    kidx[o] = i0; kidx[o + 1] = i1; kidx[o + 2] = i2;
    kw[o] = w0 * inv; kw[o + 1] = w1 * inv; kw[o + 2] = w2 * inv;
}

// ---------------- stage kernels --------------------------------------------
// stage A: fps0 (blocks 0..3) || lin_in (8192) || zero h-bufs + ctrs (1792)
__global__ __launch_bounds__(256) void stage_a_kernel(
    const float* __restrict__ pos, float* __restrict__ q1,
    const float* __restrict__ x, const float* __restrict__ lin_w,
    const float* __restrict__ lin_b, float* __restrict__ xb,
    float* __restrict__ hbuf, unsigned* __restrict__ ctrs) {
    __shared__ __align__(16) char smem[57408];
    const int blk = blockIdx.x;
    if (blk < 4) {
        fps_role<4096, 256>(pos, q1, 2048, blk, smem);
    } else if (blk < 4 + 8192) {
        lin_role(x, lin_w, lin_b, xb, blk - 4);
    } else {
        const int i = blk - 8196;
        *(float4*)(hbuf + (size_t)i * 1024 + threadIdx.x * 4) =
            make_float4(0.f, 0.f, 0.f, 0.f);
        if (i == 0 && threadIdx.x < 3) ctrs[threadIdx.x * 16] = 0u;
    }
}

// stage B: fps1 (0..3) || nbr level-0 (4096) || knn step-2 (64)
__global__ __launch_bounds__(256) void stage_b_kernel(
    const float* __restrict__ q1, float* __restrict__ q2,
    const float* __restrict__ pos, int2* __restrict__ pairs1,
    unsigned* __restrict__ ctr0,
    int* __restrict__ kidx2, float* __restrict__ kw2) {
    __shared__ __align__(16) char smem[32768];
    const int blk = blockIdx.x;
    if (blk < 4) fps_role<2048, 256>(q1, q2, 1024, blk, smem);
    else if (blk < 4 + 4096)
        nbr_role<64, 2>(pos, q1, pairs1, ctr0, 4096, 2048, blk - 4, smem);
    else
        knn_role(pos, q1, kidx2, kw2, 4096, 2048, blk - 4100);
}

// stage C: fps2 (0..3) || nbr level-1 (1024) || sa level-0 (8192) || knn1 (32)
__global__ __launch_bounds__(256) void stage_c_kernel(
    const float* __restrict__ q2, float* __restrict__ q3,
    const float* __restrict__ q1, int2* __restrict__ pairs2,
    unsigned* __restrict__ ctr1,
    const float* __restrict__ xb, const float* __restrict__ pos,
    const int2* __restrict__ pairs1, const unsigned* __restrict__ ctr0,
    const float* __restrict__ w1, const float* __restrict__ b1,
    const float* __restrict__ g1, const float* __restrict__ be1,
    const float* __restrict__ w2, const float* __restrict__ b2,
    const float* __restrict__ g2, const float* __restrict__ be2,
    float* __restrict__ h1, int* __restrict__ kidx1, float* __restrict__ kw1) {
    __shared__ __align__(16) char smem[51200];
    const int blk = blockIdx.x;
    if (blk < 4) fps_role<1024, 256>(q2, q3, 512, blk, smem);
    else if (blk < 4 + 1024)
        nbr_role<32, 4>(q1, q2, pairs2, ctr1, 2048, 1024, blk - 4, smem);
    else if (blk < 4 + 1024 + 8192)
        sa_body(xb, pos, q1, pairs1, ctr0, w1, b1, g1, be1, w2, b2, g2, be2,
                h1, 11, 12, blk - 1028, smem);
    else
        knn_role(q1, q2, kidx1, kw1, 2048, 1024, blk - 9220);
}

// stage D: nbr level-2 (512) || knn step-0 (16) || sa level-1 (4096)
__global__ __launch_bounds__(256) void stage_d_kernel(
    const float* __restrict__ q2, const float* __restrict__ q3,
    int2* __restrict__ pairs3, unsigned* __restrict__ ctr2,
    const float* __restrict__ h1, const float* __restrict__ q1,
    const int2* __restrict__ pairs2, const unsigned* __restrict__ ctr1,
    const float* __restrict__ w1, const float* __restrict__ b1,
    const float* __restrict__ g1, const float* __restrict__ be1,
    const float* __restrict__ w2, const float* __restrict__ b2,
    const float* __restrict__ g2, const float* __restrict__ be2,
    float* __restrict__ h2, int* __restrict__ kidx0, float* __restrict__ kw0) {
    __shared__ __align__(16) char smem[51200];
    const int blk = blockIdx.x;
    if (blk < 512) nbr_role<16, 4>(q2, q3, pairs3, ctr2, 1024, 512, blk, smem);
    else if (blk < 512 + 16) knn_role(q2, q3, kidx0, kw0, 1024, 512, blk - 512);
    else
        sa_body(h1, q1, q2, pairs2, ctr1, w1, b1, g1, be1, w2, b2, g2, be2,
                h2, 10, 11, blk - 528, smem);
}

// ---------------- standalone sa wrapper (level 2) ---------------------------
__global__ __launch_bounds__(256) void sa_fused_kernel(
    const float* xx, const float* pts, const float* q, const int2* pairs,
    const unsigned* vcount,
    const float* w1, const float* b1, const float* g1, const float* be1,
    const float* w2, const float* b2, const float* g2, const float* be2,
    float* hout, int lm, int ln) {
    __shared__ __align__(16) char smem[51200];
    sa_body(xx, pts, q, pairs, vcount, w1, b1, g1, be1, w2, b2, g2, be2,
            hout, lm, ln, blockIdx.x, smem);
}

// ---------------- fused FP step: interp+concat -> 256x256 -> 256x128 --------
// 32 rows/block. A-tile (32x256) gathered straight into LDS; H1 overwrites A;
// weights streamed in 16-row panels. out = bn2(relu(bn1(relu(A@W1+b1))@W2+b2)).
__global__ __launch_bounds__(256) void fp_fused_kernel(
    const float* __restrict__ xc, const float* __restrict__ xs,
    const int* __restrict__ kidx, const float* __restrict__ kw,
    const float* __restrict__ w1, const float* __restrict__ b1,
    const float* __restrict__ g1, const float* __restrict__ be1,
    const float* __restrict__ w2, const float* __restrict__ b2,
    const float* __restrict__ g2, const float* __restrict__ be2,
    float* __restrict__ out, int lnf) {
    __shared__ __align__(16) float shA[32][260];   // stride 260: 16B-aligned rows
    __shared__ __align__(16) float shW[16][256];
    const int t = threadIdx.x;
    const int r0 = blockIdx.x * 32;
    const float invs = 1.0f / sqrtf(1.0f + EPSF);

    // ---- stage A: cols 0..127 = knn-interp of xc, cols 128..255 = xs -------
    for (int e = t; e < 32 * 64; e += 256) {
        int r = e >> 6, cid = e & 63;
        int fr = r0 + r;
        float4 v;
        if (cid < 32) {
            int b = fr >> lnf;
            size_t o = (size_t)fr * 3;
            int i0 = kidx[o], i1 = kidx[o + 1], i2 = kidx[o + 2];
            float u0 = kw[o], u1 = kw[o + 1], u2 = kw[o + 2];
            // coarse rows are (b*nc + i); nc = nf/2 -> b*nc = (b << lnf) >> 1
            const float* X = xc + (((size_t)b << lnf) >> 1) * 128;
            const float4 A0 = *(const float4*)(X + (size_t)i0 * 128 + cid * 4);
            const float4 A1 = *(const float4*)(X + (size_t)i1 * 128 + cid * 4);
            const float4 A2 = *(const float4*)(X + (size_t)i2 * 128 + cid * 4);
            v.x = u0 * A0.x + u1 * A1.x + u2 * A2.x;
            v.y = u0 * A0.y + u1 * A1.y + u2 * A2.y;
            v.z = u0 * A0.z + u1 * A1.z + u2 * A2.z;
            v.w = u0 * A0.w + u1 * A1.w + u2 * A2.w;
        } else {
            v = *(const float4*)(xs + (size_t)fr * 128 + (cid - 32) * 4);
        }
        *(float4*)&shA[r][cid * 4] = v;
    }
    __syncthreads();

    // ---- layer 1: 256 -> 256 (rows 4*tr.., cols 8*tc..) --------------------
    const int tr = t >> 5, tc = t & 31;
    float acc[32];
#pragma unroll
    for (int i = 0; i < 32; ++i) acc[i] = 0.0f;
    for (int k0 = 0; k0 < 256; k0 += 16) {
        for (int e = t; e < 16 * 64; e += 256) {
            int kk = e >> 6, cid = e & 63;
            *(float4*)&shW[kk][cid * 4] =
                *(const float4*)(w1 + (size_t)(k0 + kk) * 256 + cid * 4);
        }
        __syncthreads();
        for (int kk = 0; kk < 16; ++kk) {
            const int k = k0 + kk;
            float a0 = shA[4 * tr + 0][k], a1 = shA[4 * tr + 1][k];
            float a2 = shA[4 * tr + 2][k], a3 = shA[4 * tr + 3][k];
            const float4 w0v = *(const float4*)&shW[kk][8 * tc];
            const float4 w1v = *(const float4*)&shW[kk][8 * tc + 4];
            const float wa[8] = {w0v.x, w0v.y, w0v.z, w0v.w, w1v.x, w1v.y, w1v.z, w1v.w};
#pragma unroll
            for (int j = 0; j < 8; ++j) {
                acc[0 * 8 + j] = fmaf(a0, wa[j], acc[0 * 8 + j]);
                acc[1 * 8 + j] = fmaf(a1, wa[j], acc[1 * 8 + j]);
                acc[2 * 8 + j] = fmaf(a2, wa[j], acc[2 * 8 + j]);
                acc[3 * 8 + j] = fmaf(a3, wa[j], acc[3 * 8 + j]);
            }
        }
        __syncthreads();
    }
    // epilogue 1 -> H1 overwrites shA
#pragma unroll
    for (int i = 0; i < 4; ++i)
#pragma unroll
        for (int j = 0; j < 8; ++j) {
            int col = 8 * tc + j;
            float z = fmaxf(acc[i * 8 + j] + b1[col], 0.0f);
            shA[4 * tr + i][col] = g1[col] * z * invs + be1[col];
        }
    __syncthreads();

    // ---- layer 2: 256 -> 128 (rows 2*tr2.., cols 8*tc2..) ------------------
    const int tr2 = t >> 4, tc2 = t & 15;
    float acc2[16];
#pragma unroll
    for (int i = 0; i < 16; ++i) acc2[i] = 0.0f;
    for (int k0 = 0; k0 < 256; k0 += 16) {
        for (int e = t; e < 16 * 32; e += 256) {
            int kk = e >> 5, cid = e & 31;
            *(float4*)&shW[kk][cid * 4] =
                *(const float4*)(w2 + (size_t)(k0 + kk) * 128 + cid * 4);
        }
        __syncthreads();
        for (int kk = 0; kk < 16; ++kk) {
            const int k = k0 + kk;
            float a0 = shA[2 * tr2 + 0][k], a1 = shA[2 * tr2 + 1][k];
            const float4 w0v = *(const float4*)&shW[kk][8 * tc2];
            const float4 w1v = *(const float4*)&shW[kk][8 * tc2 + 4];
            const float wa[8] = {w0v.x, w0v.y, w0v.z, w0v.w, w1v.x, w1v.y, w1v.z, w1v.w};
#pragma unroll
            for (int j = 0; j < 8; ++j) {
                acc2[0 * 8 + j] = fmaf(a0, wa[j], acc2[0 * 8 + j]);
                acc2[1 * 8 + j] = fmaf(a1, wa[j], acc2[1 * 8 + j]);
            }
        }
        __syncthreads();
    }
#pragma unroll
    for (int i = 0; i < 2; ++i)
#pragma unroll
        for (int j = 0; j < 8; ++j) {
            int col = 8 * tc2 + j;
            int fr = r0 + 2 * tr2 + i;
            float z = fmaxf(acc2[i * 8 + j] + b2[col], 0.0f);
            out[(size_t)fr * 128 + col] = g2[col] * z * invs + be2[col];
        }
}

// ---------------- generic GEMM + bias + relu + BN epilogue ------------------
__global__ __launch_bounds__(256) void gemm_bn_kernel(
    const float* __restrict__ A, const float* __restrict__ W,
    const float* __restrict__ bias, const float* __restrict__ g,
    const float* __restrict__ be, float* __restrict__ C, int Kin, int Cout) {
    __shared__ __align__(16) float shA[64][33];
    __shared__ __align__(16) float shB[32][68];
    const int t = threadIdx.x;
    const int r0 = blockIdx.x * 64;
    const int c0 = blockIdx.y * 64;
    const int tr = t >> 4, tc = t & 15;
    const float invs = 1.0f / sqrtf(1.0f + EPSF);
    float acc[16];
#pragma unroll
    for (int i = 0; i < 16; ++i) acc[i] = 0.0f;
    for (int k0 = 0; k0 < Kin; k0 += 32) {
#pragma unroll
        for (int e = t; e < 2048; e += 256) {
            int r = e >> 5, kk = e & 31;
            shA[r][kk] = A[(size_t)(r0 + r) * Kin + k0 + kk];
        }
#pragma unroll
        for (int e = t; e < 2048; e += 256) {
            int kk = e >> 6, cc = e & 63;
            shB[kk][cc] = W[(size_t)(k0 + kk) * Cout + c0 + cc];
        }
        __syncthreads();
        for (int kk = 0; kk < 32; ++kk) {
            float av[4];
#pragma unroll
            for (int i = 0; i < 4; ++i) av[i] = shA[4 * tr + i][kk];
            const float4 wv = *(const float4*)&shB[kk][4 * tc];
            const float wa[4] = {wv.x, wv.y, wv.z, wv.w};
#pragma unroll
            for (int i = 0; i < 4; ++i)
#pragma unroll
                for (int jj = 0; jj < 4; ++jj)
                    acc[i * 4 + jj] = fmaf(av[i], wa[jj], acc[i * 4 + jj]);
        }
        __syncthreads();
    }
#pragma unroll
    for (int i = 0; i < 4; ++i)
#pragma unroll
        for (int jj = 0; jj < 4; ++jj) {
            int col = c0 + 4 * tc + jj;
            float z = fmaxf(acc[i * 4 + jj] + bias[col], 0.0f);
            C[(size_t)(r0 + 4 * tr + i) * Cout + col] = g[col] * z * invs + be[col];
        }
}

// ---------------- final 128 -> 2 layer --------------------------------------
__global__ __launch_bounds__(256) void lo2_kernel(
    const float* __restrict__ in, const float* __restrict__ w,
    const float* __restrict__ b, const float* __restrict__ g,
    const float* __restrict__ be, float* __restrict__ out) {
    __shared__ float sw[256];
    const int t = threadIdx.x;
    sw[t] = w[t];
    __syncthreads();
    const int row = blockIdx.x * 256 + t;
    const float invs = 1.0f / sqrtf(1.0f + EPSF);
    float a0 = b[0], a1 = b[1];
    const float* R = in + (size_t)row * 128;
    for (int k = 0; k < 128; ++k) {
        float a = R[k];
        a0 = fmaf(a, sw[k * 2], a0);
        a1 = fmaf(a, sw[k * 2 + 1], a1);
    }
    a0 = fmaxf(a0, 0.0f);
    a1 = fmaxf(a1, 0.0f);
    out[(size_t)row * 2]     = g[0] * a0 * invs + be[0];
    out[(size_t)row * 2 + 1] = g[1] * a1 * invs + be[1];
}

// ---------------------------------------------------------------------------
extern "C" void kernel_launch(void* const* d_in, const int* in_sizes, int n_in,
                              void* d_out, int out_size, void* d_ws, size_t ws_size,
                              hipStream_t stream) {
    const float* x      = (const float*)d_in[0];
    const float* pos    = (const float*)d_in[1];
    const float* lin_w  = (const float*)d_in[3];
    const float* lin_b  = (const float*)d_in[4];
    const float* sa_w1  = (const float*)d_in[5];
    const float* sa_b1  = (const float*)d_in[6];
    const float* sa_g1  = (const float*)d_in[7];
    const float* sa_be1 = (const float*)d_in[8];
    const float* sa_w2  = (const float*)d_in[9];
    const float* sa_b2  = (const float*)d_in[10];
    const float* sa_g2  = (const float*)d_in[11];
    const float* sa_be2 = (const float*)d_in[12];
    const float* fp_w1  = (const float*)d_in[13];
    const float* fp_b1  = (const float*)d_in[14];
    const float* fp_g1  = (const float*)d_in[15];
    const float* fp_be1 = (const float*)d_in[16];
    const float* fp_w2  = (const float*)d_in[17];
    const float* fp_b2  = (const float*)d_in[18];
    const float* fp_g2  = (const float*)d_in[19];
    const float* fp_be2 = (const float*)d_in[20];
    const float* lo_w1  = (const float*)d_in[21];
    const float* lo_b1  = (const float*)d_in[22];
    const float* lo_g1  = (const float*)d_in[23];
    const float* lo_be1 = (const float*)d_in[24];
    const float* lo_w2  = (const float*)d_in[25];
    const float* lo_b2  = (const float*)d_in[26];
    const float* lo_g2  = (const float*)d_in[27];
    const float* lo_be2 = (const float*)d_in[28];

    float* ws = (float*)d_ws;
    size_t off = 0;
    auto alloc = [&](size_t n) { float* p = ws + off; off += n; return p; };
    float* xb    = alloc(4 * 4096 * 128);
    float* q1    = alloc(4 * 2048 * 3);
    float* q2    = alloc(4 * 1024 * 3);
    float* q3    = alloc(4 * 512 * 3);
    float* h1    = alloc(4 * 2048 * 128);   // h1,h2,h3 contiguous for zero role
    float* h2    = alloc(4 * 1024 * 128);
    float* h3    = alloc(4 * 512 * 128);
    int2* pairs1 = (int2*)alloc(4 * 2048 * 64 * 2);
    int2* pairs2 = (int2*)alloc(4 * 1024 * 64 * 2);
    int2* pairs3 = (int2*)alloc(4 * 512 * 64 * 2);
    unsigned* ctrs = (unsigned*)alloc(64);   // [0],[16],[32] per level
    int* kidx0   = (int*)alloc(4 * 1024 * 3);
    float* kw0   = alloc(4 * 1024 * 3);
    int* kidx1   = (int*)alloc(4 * 2048 * 3);
    float* kw1   = alloc(4 * 2048 * 3);
    int* kidx2   = (int*)alloc(4 * 4096 * 3);
    float* kw2   = alloc(4 * 4096 * 3);
    float* mbuf  = alloc(4 * 4096 * 128);
    float* xfA   = alloc(4 * 4096 * 128);
    float* xfB   = alloc(4 * 4096 * 128);
    if (ws_size < off * sizeof(float)) return;

    // stage A: fps0 || lin_in || zero (h1|h2|h3 = 4*3584*128 = 1792*1024 floats)
    stage_a_kernel<<<4 + 8192 + 1792, 256, 0, stream>>>(
        pos, q1, x, lin_w, lin_b, xb, h1, ctrs);

    // stage B: fps1 || nbr0 || knn2
    stage_b_kernel<<<4 + 4096 + 64, 256, 0, stream>>>(
        q1, q2, pos, pairs1, ctrs + 0, kidx2, kw2);

    // stage C: fps2 || nbr1 || sa0 || knn1
    stage_c_kernel<<<4 + 1024 + 8192 + 32, 256, 0, stream>>>(
        q2, q3, q1, pairs2, ctrs + 16,
        xb, pos, pairs1, ctrs + 0,
        sa_w1, sa_b1, sa_g1, sa_be1, sa_w2, sa_b2, sa_g2, sa_be2, h1,
        kidx1, kw1);

    // stage D: nbr2 || knn0 || sa1
    stage_d_kernel<<<512 + 16 + 4096, 256, 0, stream>>>(
        q2, q3, pairs3, ctrs + 32,
        h1, q1, pairs2, ctrs + 16,
        sa_w1 + 131 * 131, sa_b1 + 131, sa_g1 + 131, sa_be1 + 131,
        sa_w2 + 131 * 128, sa_b2 + 128, sa_g2 + 128, sa_be2 + 128, h2,
        kidx0, kw0);

    // sa level 2
    sa_fused_kernel<<<2048, 256, 0, stream>>>(h2, q2, q3, pairs3, ctrs + 32,
        sa_w1 + 2 * 131 * 131, sa_b1 + 2 * 131, sa_g1 + 2 * 131, sa_be1 + 2 * 131,
        sa_w2 + 2 * 131 * 128, sa_b2 + 2 * 128, sa_g2 + 2 * 128, sa_be2 + 2 * 128,
        h3, 9, 10);

    // ---- FP step 0 (mi=2): 512 -> 1024, fused ----
    fp_fused_kernel<<<4 * 1024 / 32, 256, 0, stream>>>(h3, h2, kidx0, kw0,
        fp_w1 + 2 * 256 * 256, fp_b1 + 2 * 256, fp_g1 + 2 * 256, fp_be1 + 2 * 256,
        fp_w2 + 2 * 256 * 128, fp_b2 + 2 * 128, fp_g2 + 2 * 128, fp_be2 + 2 * 128,
        xfA, 10);

    // ---- FP step 1 (mi=1): 1024 -> 2048, fused ----
    fp_fused_kernel<<<4 * 2048 / 32, 256, 0, stream>>>(xfA, h1, kidx1, kw1,
        fp_w1 + 256 * 256, fp_b1 + 256, fp_g1 + 256, fp_be1 + 256,
        fp_w2 + 256 * 128, fp_b2 + 128, fp_g2 + 128, fp_be2 + 128,
        xfB, 11);

    // ---- FP step 2 (mi=0): 2048 -> 4096, fused ----
    fp_fused_kernel<<<4 * 4096 / 32, 256, 0, stream>>>(xfB, xb, kidx2, kw2,
        fp_w1, fp_b1, fp_g1, fp_be1, fp_w2, fp_b2, fp_g2, fp_be2,
        xfA, 12);

    // ---- output MLP ----
    gemm_bn_kernel<<<dim3(16384 / 64, 2), 256, 0, stream>>>(xfA,
        lo_w1, lo_b1, lo_g1, lo_be1, mbuf, 128, 128);
    lo2_kernel<<<16384 / 256, 256, 0, stream>>>(mbuf, lo_w2, lo_b2, lo_g2, lo_be2,
        (float*)d_out);
}

// Round 12
// 3498.231 us; speedup vs baseline: 1.3197x; 1.0061x over previous
//
#include <hip/hip_runtime.h>
#include <cstddef>

// ---------------------------------------------------------------------------
// PointNet++ (B=4, N0=4096, NIN=16, NH=128, NOUT=2, DEPTH=3, K=64, R=2, KNN=3)
// fp32. Selection paths (FPS argmax, radius top-K, 3-NN) use non-contracted
// fp32 ops + first-index tie-breaks to match the reference bit-for-bit.
// FPS = round-7 proven structure, NT=256 PINNED (NT=512 failed twice: r6
// deterministic, r11 intermittent -- do not revisit). Stage kernels overlap
// the serial FPS chain with nbr/sa/knn of the previous level. FP steps fused
// (interp+concat+MLP in one kernel). Round 12: lo1+lo2 fused (bit-identical
// accumulation order), mbuf round-trip eliminated.
// ---------------------------------------------------------------------------

#define EPSF 1e-5f

__device__ __forceinline__ float d2_rn(float dx, float dy, float dz) {
    return __fadd_rn(__fadd_rn(__fmul_rn(dx, dx), __fmul_rn(dy, dy)), __fmul_rn(dz, dz));
}

template <int CTRL, int RMASK>
__device__ __forceinline__ float dpp_max_f32(float v) {
    int o = __builtin_amdgcn_update_dpp(__float_as_int(v), __float_as_int(v),
                                        CTRL, RMASK, 0xf, false);
    return fmaxf(v, __int_as_float(o));
}

// ---------------- FPS role (round-7 math verbatim; NT=256) ------------------
template <int N, int NT>
__device__ void fps_role(const float* __restrict__ pts, float* __restrict__ q,
                         const int m, const int b, char* smem) {
    constexpr int PPT = N / NT;
    constexpr int NW = NT / 64;
    float* s_px = (float*)smem;
    float* s_py = s_px + N;
    float* s_pz = s_py + N;
    int*   s_qi = (int*)(s_pz + N);
    float2* s_slot = (float2*)(s_qi + N / 2);   // [2][NW]
    const int t = threadIdx.x;
    const int wave = t >> 6, lane = t & 63;
    const int base = t * PPT;                    // blocked assignment
    const float* P = pts + (size_t)b * N * 3;
    asm volatile("s_setprio 3");                 // protect serial chain
    float rx[PPT], ry[PPT], rz[PPT], dmin[PPT];
#pragma unroll
    for (int j = 0; j < PPT; ++j) {
        int i = base + j;
        float x = P[i * 3], y = P[i * 3 + 1], z = P[i * 3 + 2];
        rx[j] = x; ry[j] = y; rz[j] = z; dmin[j] = 1e30f;
        s_px[i] = x; s_py[i] = y; s_pz[i] = z;
    }
    float lx = P[0], ly = P[1], lz = P[2];
    if (t == 0) s_qi[0] = 0;

    for (int step = 1; step < m; ++step) {
        float bv = -1.0f; int bj = 0;
#pragma unroll
        for (int j = 0; j < PPT; ++j) {
            float d = d2_rn(rx[j] - lx, ry[j] - ly, rz[j] - lz);
            float dm = fminf(dmin[j], d);
            dmin[j] = dm;
            if (dm > bv) { bv = dm; bj = j; }   // strict >: first (lowest) index
        }
        const int bidx = base + bj;

        float v = bv;
        v = dpp_max_f32<0x111, 0xf>(v);   // row_shr:1
        v = dpp_max_f32<0x112, 0xf>(v);   // row_shr:2
        v = dpp_max_f32<0x114, 0xf>(v);   // row_shr:4
        v = dpp_max_f32<0x118, 0xf>(v);   // row_shr:8
        v = dpp_max_f32<0x142, 0xa>(v);   // row_bcast:15
        v = dpp_max_f32<0x143, 0xc>(v);   // row_bcast:31
        const float mv = __int_as_float(__builtin_amdgcn_readlane(__float_as_int(v), 63));
        unsigned long long mb = __ballot(bv == mv);
        const int wl = __ffsll((long long)mb) - 1;
        const int wbi = __builtin_amdgcn_readlane(bidx, wl);

        const int p = step & 1;
        if (lane == 0) s_slot[p * NW + wave] = make_float2(mv, __int_as_float(wbi));
        __syncthreads();

        float2 sl = s_slot[p * NW + (lane & (NW - 1))];
        float gvt = sl.x;
        gvt = dpp_max_f32<0x111, 0xf>(gvt);
        gvt = dpp_max_f32<0x112, 0xf>(gvt);
        if (NW == 8) gvt = dpp_max_f32<0x114, 0xf>(gvt);
        const float gm = __int_as_float(
            __builtin_amdgcn_readlane(__float_as_int(gvt), NW - 1));
        unsigned long long gb = __ballot((lane < NW) && (sl.x == gm));
        const int gl = __ffsll((long long)gb) - 1;        // lowest slot == lowest index
        const int gi = __builtin_amdgcn_readlane(__float_as_int(sl.y), gl);

        lx = s_px[gi]; ly = s_py[gi]; lz = s_pz[gi];      // broadcast reads
        if (t == 0) s_qi[step] = gi;
    }
    __syncthreads();
    for (int e = t; e < m; e += NT) {
        int gi = s_qi[e];
        size_t o = ((size_t)b * m + e) * 3;
        q[o] = s_px[gi]; q[o + 1] = s_py[gi]; q[o + 2] = s_pz[gi];
    }
}

// ---------------- lin_in role: 2 rows per 256-thread block ------------------
__device__ void lin_role(const float* __restrict__ x, const float* __restrict__ w,
                         const float* __restrict__ bias, float* __restrict__ xb,
                         const int blk) {
    const int t = threadIdx.x;
    const int row = blk * 2 + (t >> 7);
    const int col = t & 127;
    float acc = bias[col];
#pragma unroll
    for (int k = 0; k < 16; ++k) acc = fmaf(x[row * 16 + k], w[k * 128 + col], acc);
    xb[row * 128 + col] = fmaxf(acc, 0.0f);
}

// ---------------- nbr role: radius-ball K=64 -> compacted pair list ---------
template <int CHUNK, int WACT>
__device__ void nbr_role(const float* __restrict__ pts, const float* __restrict__ q,
                         int2* __restrict__ pairs, unsigned* __restrict__ counter,
                         const int n, const int m, const int blk, char* smem) {
    const int w = threadIdx.x >> 6, lane = threadIdx.x & 63;
    if (w >= WACT) return;
    float* D = (float*)smem + w * CHUNK * 64;
    const int c = blk * WACT + w;
    const int b = c / m;
    const float* P = pts + (size_t)b * n * 3;
    const float qx = q[(size_t)c * 3 + 0];
    const float qy = q[(size_t)c * 3 + 1];
    const float qz = q[(size_t)c * 3 + 2];
    for (int s = 0; s < CHUNK; ++s) {
        int i = s * 64 + lane;
        float d2 = d2_rn(P[i * 3] - qx, P[i * 3 + 1] - qy, P[i * 3 + 2] - qz);
        D[i] = (d2 <= 4.0f) ? d2 : 1e30f;   // RADIUS^2 = 4
    }
    int my_g = -1;
    int cnt = 0;
    for (int round = 0; round < 64; ++round) {
        float bv = 3e38f;
        int bi = 0x7fffffff;
        for (int s = 0; s < CHUNK; ++s) {
            int i = s * 64 + lane;
            float v = D[i];
            if (v < bv) { bv = v; bi = i; }   // strict <: lowest-index tie-break
        }
#pragma unroll
        for (int off = 32; off >= 1; off >>= 1) {
            float ov = __shfl_xor(bv, off, 64);
            int   oi = __shfl_xor(bi, off, 64);
            if (ov < bv || (ov == bv && oi < bi)) { bv = ov; bi = oi; }
        }
        if (bv > 1e29f) break;               // only invalid/removed remain (uniform)
        if (round == lane) my_g = bi;
        if (lane == (bi & 63)) D[bi] = 3e38f;
        ++cnt;
    }
    unsigned base = 0;
    if (lane == 0) base = atomicAdd(counter, (unsigned)cnt);
    base = (unsigned)__shfl((int)base, 0, 64);
    if (lane < cnt) pairs[base + lane] = make_int2(c, my_g);
}

// ---------------- SA MLP body over compacted rows (256 threads) -------------
typedef float Row132[132];
__device__ void sa_body(const float* __restrict__ xx, const float* __restrict__ pts,
    const float* __restrict__ q, const int2* __restrict__ pairs,
    const unsigned* __restrict__ vcount,
    const float* __restrict__ w1, const float* __restrict__ b1,
    const float* __restrict__ g1, const float* __restrict__ be1,
    const float* __restrict__ w2, const float* __restrict__ b2,
    const float* __restrict__ g2, const float* __restrict__ be2,
    float* __restrict__ hout, const int lm, const int ln, const int blk, char* smem) {
    Row132* shA = (Row132*)smem;                    // 64 rows: 33792 B
    Row132* shW = (Row132*)(smem + 33792);          // 32 rows: 16896 B
    int* sh_c = (int*)(smem + 50688);
    int* sh_g = sh_c + 64;
    const int t = threadIdx.x;
    const int V = (int)*vcount;
    const int r0 = blk * 64;
    if (r0 >= V) return;
    if (t < 64) {
        int r = r0 + t;
        if (r < V) { int2 p = pairs[r]; sh_c[t] = p.x; sh_g[t] = p.y; }
        else { sh_c[t] = -1; sh_g[t] = 0; }
    }
    __syncthreads();

    for (int e = t; e < 64 * 33; e += 256) {
        int row = e / 33, cid = e - row * 33;
        int c = sh_c[row];
        float4 v = make_float4(0.f, 0.f, 0.f, 0.f);
        if (c >= 0) {
            int g = sh_g[row];
            int b = c >> lm;
            size_t pt = ((size_t)(b << ln) + g);
            if (cid < 32) {
                v = *(const float4*)(xx + (pt << 7) + cid * 4);
            } else {
                const float* P = pts + pt * 3;
                const float* Q = q + (size_t)c * 3;
                v.x = P[0] - Q[0]; v.y = P[1] - Q[1]; v.z = P[2] - Q[2]; v.w = 0.f;
            }
        }
        *(float4*)&shA[row][cid * 4] = v;
    }
    __syncthreads();

    const float invs = 1.0f / sqrtf(1.0f + EPSF);
    const int tr = t >> 4, tc = t & 15;
    const int xrow = t >> 2, xcol = t & 3;
    float acc[32];
#pragma unroll
    for (int i = 0; i < 32; ++i) acc[i] = 0.0f;
    float accx = 0.0f;

    for (int k0 = 0; k0 < 132; k0 += 32) {
        const int kc = (132 - k0 < 32) ? (132 - k0) : 32;
        for (int e = t; e < kc * 132; e += 256) {
            int kk = e / 132, j = e - kk * 132;
            int k = k0 + kk;
            shW[kk][j] = (k < 131 && j < 131) ? w1[k * 131 + j] : 0.0f;
        }
        __syncthreads();
        for (int kk = 0; kk < kc; ++kk) {
            const int k = k0 + kk;
            float a0 = shA[4 * tr + 0][k], a1 = shA[4 * tr + 1][k];
            float a2 = shA[4 * tr + 2][k], a3 = shA[4 * tr + 3][k];
            const float4 w0 = *(const float4*)&shW[kk][8 * tc];
            const float4 w1v = *(const float4*)&shW[kk][8 * tc + 4];
            const float wa[8] = {w0.x, w0.y, w0.z, w0.w, w1v.x, w1v.y, w1v.z, w1v.w};
#pragma unroll
            for (int j = 0; j < 8; ++j) {
                acc[0 * 8 + j] = fmaf(a0, wa[j], acc[0 * 8 + j]);
                acc[1 * 8 + j] = fmaf(a1, wa[j], acc[1 * 8 + j]);
                acc[2 * 8 + j] = fmaf(a2, wa[j], acc[2 * 8 + j]);
                acc[3 * 8 + j] = fmaf(a3, wa[j], acc[3 * 8 + j]);
            }
            accx = fmaf(shA[xrow][k], shW[kk][128 + xcol], accx);
        }
        __syncthreads();
    }
#pragma unroll
    for (int i = 0; i < 4; ++i)
#pragma unroll
        for (int j = 0; j < 8; ++j) {
            int col = 8 * tc + j;
            float z = fmaxf(acc[i * 8 + j] + b1[col], 0.0f);
            shA[4 * tr + i][col] = g1[col] * z * invs + be1[col];
        }
    if (xcol < 3) {
        int col = 128 + xcol;
        float z = fmaxf(accx + b1[col], 0.0f);
        shA[xrow][col] = g1[col] * z * invs + be1[col];
    } else {
        shA[xrow][131] = 0.0f;
    }

#pragma unroll
    for (int i = 0; i < 32; ++i) acc[i] = 0.0f;
    for (int k0 = 0; k0 < 132; k0 += 32) {
        const int kc = (132 - k0 < 32) ? (132 - k0) : 32;
        for (int e = t; e < kc * 132; e += 256) {
            int kk = e / 132, j = e - kk * 132;
            int k = k0 + kk;
            shW[kk][j] = (k < 131 && j < 128) ? w2[k * 128 + j] : 0.0f;
        }
        __syncthreads();
        for (int kk = 0; kk < kc; ++kk) {
            const int k = k0 + kk;
            float a0 = shA[4 * tr + 0][k], a1 = shA[4 * tr + 1][k];
            float a2 = shA[4 * tr + 2][k], a3 = shA[4 * tr + 3][k];
            const float4 w0 = *(const float4*)&shW[kk][8 * tc];
            const float4 w1v = *(const float4*)&shW[kk][8 * tc + 4];
            const float wa[8] = {w0.x, w0.y, w0.z, w0.w, w1v.x, w1v.y, w1v.z, w1v.w};
#pragma unroll
            for (int j = 0; j < 8; ++j) {
                acc[0 * 8 + j] = fmaf(a0, wa[j], acc[0 * 8 + j]);
                acc[1 * 8 + j] = fmaf(a1, wa[j], acc[1 * 8 + j]);
                acc[2 * 8 + j] = fmaf(a2, wa[j], acc[2 * 8 + j]);
                acc[3 * 8 + j] = fmaf(a3, wa[j], acc[3 * 8 + j]);
            }
        }
        __syncthreads();
    }
#pragma unroll
    for (int i = 0; i < 4; ++i)
#pragma unroll
        for (int j = 0; j < 8; ++j) {
            int col = 8 * tc + j;
            float z = fmaxf(acc[i * 8 + j] + b2[col], 0.0f);
            shA[4 * tr + i][col] = g2[col] * z * invs + be2[col];
        }
    __syncthreads();

    if (t < 128) {
        const int col = t;
        float run = -1.0f;
        int cur = sh_c[0];
        for (int row = 0; row < 64; ++row) {
            int c = sh_c[row];
            if (c != cur) {
                if (cur >= 0)
                    atomicMax((unsigned*)&hout[((size_t)cur << 7) + col], __float_as_uint(run));
                run = -1.0f; cur = c;
            }
            run = fmaxf(run, shA[row][col]);
        }
        if (cur >= 0)
            atomicMax((unsigned*)&hout[((size_t)cur << 7) + col], __float_as_uint(run));
    }
}

// ---------------- knn role: 3-NN search + inverse-d2 weights ----------------
__device__ void knn_role(const float* __restrict__ pf, const float* __restrict__ pc,
                         int* __restrict__ kidx, float* __restrict__ kw,
                         const int nf, const int nc, const int blk) {
    const int tg = blk * 256 + threadIdx.x;
    const int b = tg / nf;
    const float* F = pf + (size_t)tg * 3;
    const float fx = F[0], fy = F[1], fz = F[2];
    const float* C = pc + (size_t)b * nc * 3;
    float b0 = 1e30f, b1 = 1e30f, b2 = 1e30f;
    int i0 = 0, i1 = 0, i2 = 0;
    for (int j = 0; j < nc; ++j) {
        float d2 = d2_rn(C[j * 3] - fx, C[j * 3 + 1] - fy, C[j * 3 + 2] - fz);
        if (d2 < b0)      { b2 = b1; i2 = i1; b1 = b0; i1 = i0; b0 = d2; i0 = j; }
        else if (d2 < b1) { b2 = b1; i2 = i1; b1 = d2; i1 = j; }
        else if (d2 < b2) { b2 = d2; i2 = j; }
    }
    float w0 = 1.0f / fmaxf(b0, 1e-16f);
    float w1 = 1.0f / fmaxf(b1, 1e-16f);
    float w2 = 1.0f / fmaxf(b2, 1e-16f);
    float inv = 1.0f / (w0 + w1 + w2);
    size_t o = (size_t)tg * 3;
    kidx[o] = i0; kidx[o + 1] = i1; kidx[o + 2] = i2;
    kw[o] = w0 * inv; kw[o + 1] = w1 * inv; kw[o + 2] = w2 * inv;
}

// ---------------- stage kernels (256 threads) -------------------------------
// stage A: fps0 (0..3) || lin_in (8192) || zero h-bufs + ctrs (1792)
__global__ __launch_bounds__(256) void stage_a_kernel(
    const float* __restrict__ pos, float* __restrict__ q1,
    const float* __restrict__ x, const float* __restrict__ lin_w,
    const float* __restrict__ lin_b, float* __restrict__ xb,
    float* __restrict__ hbuf, unsigned* __restrict__ ctrs) {
    __shared__ __align__(16) char smem[57408];
    const int blk = blockIdx.x;
    if (blk < 4) {
        fps_role<4096, 256>(pos, q1, 2048, blk, smem);
    } else if (blk < 4 + 8192) {
        lin_role(x, lin_w, lin_b, xb, blk - 4);
    } else {
        const int i = blk - 8196;
        *(float4*)(hbuf + (size_t)i * 1024 + threadIdx.x * 4) =
            make_float4(0.f, 0.f, 0.f, 0.f);
        if (i == 0 && threadIdx.x < 3) ctrs[threadIdx.x * 16] = 0u;
    }
}

// stage B: fps1 (0..3) || nbr level-0 (4096) || knn step-2 (64)
__global__ __launch_bounds__(256) void stage_b_kernel(
    const float* __restrict__ q1, float* __restrict__ q2,
    const float* __restrict__ pos, int2* __restrict__ pairs1,
    unsigned* __restrict__ ctr0,
    int* __restrict__ kidx2, float* __restrict__ kw2) {
    __shared__ __align__(16) char smem[32768];
    const int blk = blockIdx.x;
    if (blk < 4) fps_role<2048, 256>(q1, q2, 1024, blk, smem);
    else if (blk < 4 + 4096)
        nbr_role<64, 2>(pos, q1, pairs1, ctr0, 4096, 2048, blk - 4, smem);
    else
        knn_role(pos, q1, kidx2, kw2, 4096, 2048, blk - 4100);
}

// stage C: fps2 (0..3) || nbr level-1 (1024) || sa level-0 (8192) || knn1 (32)
__global__ __launch_bounds__(256) void stage_c_kernel(
    const float* __restrict__ q2, float* __restrict__ q3,
    const float* __restrict__ q1, int2* __restrict__ pairs2,
    unsigned* __restrict__ ctr1,
    const float* __restrict__ xb, const float* __restrict__ pos,
    const int2* __restrict__ pairs1, const unsigned* __restrict__ ctr0,
    const float* __restrict__ w1, const float* __restrict__ b1,
    const float* __restrict__ g1, const float* __restrict__ be1,
    const float* __restrict__ w2, const float* __restrict__ b2,
    const float* __restrict__ g2, const float* __restrict__ be2,
    float* __restrict__ h1, int* __restrict__ kidx1, float* __restrict__ kw1) {
    __shared__ __align__(16) char smem[51200];
    const int blk = blockIdx.x;
    if (blk < 4) fps_role<1024, 256>(q2, q3, 512, blk, smem);
    else if (blk < 4 + 1024)
        nbr_role<32, 4>(q1, q2, pairs2, ctr1, 2048, 1024, blk - 4, smem);
    else if (blk < 4 + 1024 + 8192)
        sa_body(xb, pos, q1, pairs1, ctr0, w1, b1, g1, be1, w2, b2, g2, be2,
                h1, 11, 12, blk - 1028, smem);
    else
        knn_role(q1, q2, kidx1, kw1, 2048, 1024, blk - 9220);
}

// stage D: nbr level-2 (512) || knn step-0 (16) || sa level-1 (4096)
__global__ __launch_bounds__(256) void stage_d_kernel(
    const float* __restrict__ q2, const float* __restrict__ q3,
    int2* __restrict__ pairs3, unsigned* __restrict__ ctr2,
    const float* __restrict__ h1, const float* __restrict__ q1,
    const int2* __restrict__ pairs2, const unsigned* __restrict__ ctr1,
    const float* __restrict__ w1, const float* __restrict__ b1,
    const float* __restrict__ g1, const float* __restrict__ be1,
    const float* __restrict__ w2, const float* __restrict__ b2,
    const float* __restrict__ g2, const float* __restrict__ be2,
    float* __restrict__ h2, int* __restrict__ kidx0, float* __restrict__ kw0) {
    __shared__ __align__(16) char smem[51200];
    const int blk = blockIdx.x;
    if (blk < 512) nbr_role<16, 4>(q2, q3, pairs3, ctr2, 1024, 512, blk, smem);
    else if (blk < 512 + 16) knn_role(q2, q3, kidx0, kw0, 1024, 512, blk - 512);
    else
        sa_body(h1, q1, q2, pairs2, ctr1, w1, b1, g1, be1, w2, b2, g2, be2,
                h2, 10, 11, blk - 528, smem);
}

// ---------------- standalone sa wrapper (level 2) ---------------------------
__global__ __launch_bounds__(256) void sa_fused_kernel(
    const float* xx, const float* pts, const float* q, const int2* pairs,
    const unsigned* vcount,
    const float* w1, const float* b1, const float* g1, const float* be1,
    const float* w2, const float* b2, const float* g2, const float* be2,
    float* hout, int lm, int ln) {
    __shared__ __align__(16) char smem[51200];
    sa_body(xx, pts, q, pairs, vcount, w1, b1, g1, be1, w2, b2, g2, be2,
            hout, lm, ln, blockIdx.x, smem);
}

// ---------------- fused FP step: interp+concat -> 256x256 -> 256x128 --------
__global__ __launch_bounds__(256) void fp_fused_kernel(
    const float* __restrict__ xc, const float* __restrict__ xs,
    const int* __restrict__ kidx, const float* __restrict__ kw,
    const float* __restrict__ w1, const float* __restrict__ b1,
    const float* __restrict__ g1, const float* __restrict__ be1,
    const float* __restrict__ w2, const float* __restrict__ b2,
    const float* __restrict__ g2, const float* __restrict__ be2,
    float* __restrict__ out, int lnf) {
    __shared__ __align__(16) float shA[32][260];
    __shared__ __align__(16) float shW[16][256];
    const int t = threadIdx.x;
    const int r0 = blockIdx.x * 32;
    const float invs = 1.0f / sqrtf(1.0f + EPSF);

    for (int e = t; e < 32 * 64; e += 256) {
        int r = e >> 6, cid = e & 63;
        int fr = r0 + r;
        float4 v;
        if (cid < 32) {
            int b = fr >> lnf;
            size_t o = (size_t)fr * 3;
            int i0 = kidx[o], i1 = kidx[o + 1], i2 = kidx[o + 2];
            float u0 = kw[o], u1 = kw[o + 1], u2 = kw[o + 2];
            const float* X = xc + (((size_t)b << lnf) >> 1) * 128;
            const float4 A0 = *(const float4*)(X + (size_t)i0 * 128 + cid * 4);
            const float4 A1 = *(const float4*)(X + (size_t)i1 * 128 + cid * 4);
            const float4 A2 = *(const float4*)(X + (size_t)i2 * 128 + cid * 4);
            v.x = u0 * A0.x + u1 * A1.x + u2 * A2.x;
            v.y = u0 * A0.y + u1 * A1.y + u2 * A2.y;
            v.z = u0 * A0.z + u1 * A1.z + u2 * A2.z;
            v.w = u0 * A0.w + u1 * A1.w + u2 * A2.w;
        } else {
            v = *(const float4*)(xs + (size_t)fr * 128 + (cid - 32) * 4);
        }
        *(float4*)&shA[r][cid * 4] = v;
    }
    __syncthreads();

    const int tr = t >> 5, tc = t & 31;
    float acc[32];
#pragma unroll
    for (int i = 0; i < 32; ++i) acc[i] = 0.0f;
    for (int k0 = 0; k0 < 256; k0 += 16) {
        for (int e = t; e < 16 * 64; e += 256) {
            int kk = e >> 6, cid = e & 63;
            *(float4*)&shW[kk][cid * 4] =
                *(const float4*)(w1 + (size_t)(k0 + kk) * 256 + cid * 4);
        }
        __syncthreads();
        for (int kk = 0; kk < 16; ++kk) {
            const int k = k0 + kk;
            float a0 = shA[4 * tr + 0][k], a1 = shA[4 * tr + 1][k];
            float a2 = shA[4 * tr + 2][k], a3 = shA[4 * tr + 3][k];
            const float4 w0v = *(const float4*)&shW[kk][8 * tc];
            const float4 w1v = *(const float4*)&shW[kk][8 * tc + 4];
            const float wa[8] = {w0v.x, w0v.y, w0v.z, w0v.w, w1v.x, w1v.y, w1v.z, w1v.w};
#pragma unroll
            for (int j = 0; j < 8; ++j) {
                acc[0 * 8 + j] = fmaf(a0, wa[j], acc[0 * 8 + j]);
                acc[1 * 8 + j] = fmaf(a1, wa[j], acc[1 * 8 + j]);
                acc[2 * 8 + j] = fmaf(a2, wa[j], acc[2 * 8 + j]);
                acc[3 * 8 + j] = fmaf(a3, wa[j], acc[3 * 8 + j]);
            }
        }
        __syncthreads();
    }
#pragma unroll
    for (int i = 0; i < 4; ++i)
#pragma unroll
        for (int j = 0; j < 8; ++j) {
            int col = 8 * tc + j;
            float z = fmaxf(acc[i * 8 + j] + b1[col], 0.0f);
            shA[4 * tr + i][col] = g1[col] * z * invs + be1[col];
        }
    __syncthreads();

    const int tr2 = t >> 4, tc2 = t & 15;
    float acc2[16];
#pragma unroll
    for (int i = 0; i < 16; ++i) acc2[i] = 0.0f;
    for (int k0 = 0; k0 < 256; k0 += 16) {
        for (int e = t; e < 16 * 32; e += 256) {
            int kk = e >> 5, cid = e & 31;
            *(float4*)&shW[kk][cid * 4] =
                *(const float4*)(w2 + (size_t)(k0 + kk) * 128 + cid * 4);
        }
        __syncthreads();
        for (int kk = 0; kk < 16; ++kk) {
            const int k = k0 + kk;
            float a0 = shA[2 * tr2 + 0][k], a1 = shA[2 * tr2 + 1][k];
            const float4 w0v = *(const float4*)&shW[kk][8 * tc2];
            const float4 w1v = *(const float4*)&shW[kk][8 * tc2 + 4];
            const float wa[8] = {w0v.x, w0v.y, w0v.z, w0v.w, w1v.x, w1v.y, w1v.z, w1v.w};
#pragma unroll
            for (int j = 0; j < 8; ++j) {
                acc2[0 * 8 + j] = fmaf(a0, wa[j], acc2[0 * 8 + j]);
                acc2[1 * 8 + j] = fmaf(a1, wa[j], acc2[1 * 8 + j]);
            }
        }
        __syncthreads();
    }
#pragma unroll
    for (int i = 0; i < 2; ++i)
#pragma unroll
        for (int j = 0; j < 8; ++j) {
            int col = 8 * tc2 + j;
            int fr = r0 + 2 * tr2 + i;
            float z = fmaxf(acc2[i * 8 + j] + b2[col], 0.0f);
            out[(size_t)fr * 128 + col] = g2[col] * z * invs + be2[col];
        }
}

// ---------------- fused output MLP: 128 -> 128 -> 2 -------------------------
// 32 rows/block. Same k-ascending accumulation order as the previous
// gemm_bn + lo2 pair: bit-identical results.
__global__ __launch_bounds__(256) void lo_fused_kernel(
    const float* __restrict__ in,
    const float* __restrict__ w1, const float* __restrict__ b1,
    const float* __restrict__ g1, const float* __restrict__ be1,
    const float* __restrict__ w2, const float* __restrict__ b2,
    const float* __restrict__ g2, const float* __restrict__ be2,
    float* __restrict__ out) {
    __shared__ __align__(16) float shA[32][132];
    __shared__ __align__(16) float shW[16][128];
    const int t = threadIdx.x;
    const int r0 = blockIdx.x * 32;
    const float invs = 1.0f / sqrtf(1.0f + EPSF);

    // load A: 32 rows x 128 cols
    for (int e = t; e < 32 * 32; e += 256) {
        int r = e >> 5, cid = e & 31;
        *(float4*)&shA[r][cid * 4] =
            *(const float4*)(in + (size_t)(r0 + r) * 128 + cid * 4);
    }
    __syncthreads();

    // layer 1: 128 -> 128. rows 2*tr+{0,1}, cols 8*tc..8*tc+7
    const int tr = t >> 4, tc = t & 15;
    float acc[16];
#pragma unroll
    for (int i = 0; i < 16; ++i) acc[i] = 0.0f;
    for (int k0 = 0; k0 < 128; k0 += 16) {
        for (int e = t; e < 16 * 32; e += 256) {
            int kk = e >> 5, cid = e & 31;
            *(float4*)&shW[kk][cid * 4] =
                *(const float4*)(w1 + (size_t)(k0 + kk) * 128 + cid * 4);
        }
        __syncthreads();
        for (int kk = 0; kk < 16; ++kk) {
            const int k = k0 + kk;
            float a0 = shA[2 * tr + 0][k], a1 = shA[2 * tr + 1][k];
            const float4 w0v = *(const float4*)&shW[kk][8 * tc];
            const float4 w1v = *(const float4*)&shW[kk][8 * tc + 4];
            const float wa[8] = {w0v.x, w0v.y, w0v.z, w0v.w, w1v.x, w1v.y, w1v.z, w1v.w};
#pragma unroll
            for (int j = 0; j < 8; ++j) {
                acc[0 * 8 + j] = fmaf(a0, wa[j], acc[0 * 8 + j]);
                acc[1 * 8 + j] = fmaf(a1, wa[j], acc[1 * 8 + j]);
            }
        }
        __syncthreads();
    }
    // epilogue 1 -> H1 overwrites shA cols 0..127
#pragma unroll
    for (int i = 0; i < 2; ++i)
#pragma unroll
        for (int j = 0; j < 8; ++j) {
            int col = 8 * tc + j;
            float z = fmaxf(acc[i * 8 + j] + b1[col], 0.0f);
            shA[2 * tr + i][col] = g1[col] * z * invs + be1[col];
        }
    __syncthreads();

    // layer 2: 128 -> 2. 64 threads: row = t>>1, col = t&1
    if (t < 64) {
        const int row = t >> 1, col = t & 1;
        float a = b2[col];
        for (int k = 0; k < 128; ++k)
            a = fmaf(shA[row][k], w2[k * 2 + col], a);
        a = fmaxf(a, 0.0f);
        out[(size_t)(r0 + row) * 2 + col] = g2[col] * a * invs + be2[col];
    }
}

// ---------------------------------------------------------------------------
extern "C" void kernel_launch(void* const* d_in, const int* in_sizes, int n_in,
                              void* d_out, int out_size, void* d_ws, size_t ws_size,
                              hipStream_t stream) {
    const float* x      = (const float*)d_in[0];
    const float* pos    = (const float*)d_in[1];
    const float* lin_w  = (const float*)d_in[3];
    const float* lin_b  = (const float*)d_in[4];
    const float* sa_w1  = (const float*)d_in[5];
    const float* sa_b1  = (const float*)d_in[6];
    const float* sa_g1  = (const float*)d_in[7];
    const float* sa_be1 = (const float*)d_in[8];
    const float* sa_w2  = (const float*)d_in[9];
    const float* sa_b2  = (const float*)d_in[10];
    const float* sa_g2  = (const float*)d_in[11];
    const float* sa_be2 = (const float*)d_in[12];
    const float* fp_w1  = (const float*)d_in[13];
    const float* fp_b1  = (const float*)d_in[14];
    const float* fp_g1  = (const float*)d_in[15];
    const float* fp_be1 = (const float*)d_in[16];
    const float* fp_w2  = (const float*)d_in[17];
    const float* fp_b2  = (const float*)d_in[18];
    const float* fp_g2  = (const float*)d_in[19];
    const float* fp_be2 = (const float*)d_in[20];
    const float* lo_w1  = (const float*)d_in[21];
    const float* lo_b1  = (const float*)d_in[22];
    const float* lo_g1  = (const float*)d_in[23];
    const float* lo_be1 = (const float*)d_in[24];
    const float* lo_w2  = (const float*)d_in[25];
    const float* lo_b2  = (const float*)d_in[26];
    const float* lo_g2  = (const float*)d_in[27];
    const float* lo_be2 = (const float*)d_in[28];

    float* ws = (float*)d_ws;
    size_t off = 0;
    auto alloc = [&](size_t n) { float* p = ws + off; off += n; return p; };
    float* xb    = alloc(4 * 4096 * 128);
    float* q1    = alloc(4 * 2048 * 3);
    float* q2    = alloc(4 * 1024 * 3);
    float* q3    = alloc(4 * 512 * 3);
    float* h1    = alloc(4 * 2048 * 128);   // h1,h2,h3 contiguous for zero role
    float* h2    = alloc(4 * 1024 * 128);
    float* h3    = alloc(4 * 512 * 128);
    int2* pairs1 = (int2*)alloc(4 * 2048 * 64 * 2);
    int2* pairs2 = (int2*)alloc(4 * 1024 * 64 * 2);
    int2* pairs3 = (int2*)alloc(4 * 512 * 64 * 2);
    unsigned* ctrs = (unsigned*)alloc(64);   // [0],[16],[32] per level
    int* kidx0   = (int*)alloc(4 * 1024 * 3);
    float* kw0   = alloc(4 * 1024 * 3);
    int* kidx1   = (int*)alloc(4 * 2048 * 3);
    float* kw1   = alloc(4 * 2048 * 3);
    int* kidx2   = (int*)alloc(4 * 4096 * 3);
    float* kw2   = alloc(4 * 4096 * 3);
    float* xfA   = alloc(4 * 4096 * 128);
    float* xfB   = alloc(4 * 4096 * 128);
    if (ws_size < off * sizeof(float)) return;

    // stage A: fps0 || lin_in || zero (h1|h2|h3 = 4*3584*128 = 1792*1024 floats)
    stage_a_kernel<<<4 + 8192 + 1792, 256, 0, stream>>>(
        pos, q1, x, lin_w, lin_b, xb, h1, ctrs);

    // stage B: fps1 || nbr0 || knn2
    stage_b_kernel<<<4 + 4096 + 64, 256, 0, stream>>>(
        q1, q2, pos, pairs1, ctrs + 0, kidx2, kw2);

    // stage C: fps2 || nbr1 || sa0 || knn1
    stage_c_kernel<<<4 + 1024 + 8192 + 32, 256, 0, stream>>>(
        q2, q3, q1, pairs2, ctrs + 16,
        xb, pos, pairs1, ctrs + 0,
        sa_w1, sa_b1, sa_g1, sa_be1, sa_w2, sa_b2, sa_g2, sa_be2, h1,
        kidx1, kw1);

    // stage D: nbr2 || knn0 || sa1
    stage_d_kernel<<<512 + 16 + 4096, 256, 0, stream>>>(
        q2, q3, pairs3, ctrs + 32,
        h1, q1, pairs2, ctrs + 16,
        sa_w1 + 131 * 131, sa_b1 + 131, sa_g1 + 131, sa_be1 + 131,
        sa_w2 + 131 * 128, sa_b2 + 128, sa_g2 + 128, sa_be2 + 128, h2,
        kidx0, kw0);

    // sa level 2
    sa_fused_kernel<<<2048, 256, 0, stream>>>(h2, q2, q3, pairs3, ctrs + 32,
        sa_w1 + 2 * 131 * 131, sa_b1 + 2 * 131, sa_g1 + 2 * 131, sa_be1 + 2 * 131,
        sa_w2 + 2 * 131 * 128, sa_b2 + 2 * 128, sa_g2 + 2 * 128, sa_be2 + 2 * 128,
        h3, 9, 10);

    // ---- FP step 0 (mi=2): 512 -> 1024, fused ----
    fp_fused_kernel<<<4 * 1024 / 32, 256, 0, stream>>>(h3, h2, kidx0, kw0,
        fp_w1 + 2 * 256 * 256, fp_b1 + 2 * 256, fp_g1 + 2 * 256, fp_be1 + 2 * 256,
        fp_w2 + 2 * 256 * 128, fp_b2 + 2 * 128, fp_g2 + 2 * 128, fp_be2 + 2 * 128,
        xfA, 10);

    // ---- FP step 1 (mi=1): 1024 -> 2048, fused ----
    fp_fused_kernel<<<4 * 2048 / 32, 256, 0, stream>>>(xfA, h1, kidx1, kw1,
        fp_w1 + 256 * 256, fp_b1 + 256, fp_g1 + 256, fp_be1 + 256,
        fp_w2 + 256 * 128, fp_b2 + 128, fp_g2 + 128, fp_be2 + 128,
        xfB, 11);

    // ---- FP step 2 (mi=0): 2048 -> 4096, fused ----
    fp_fused_kernel<<<4 * 4096 / 32, 256, 0, stream>>>(xfB, xb, kidx2, kw2,
        fp_w1, fp_b1, fp_g1, fp_be1, fp_w2, fp_b2, fp_g2, fp_be2,
        xfA, 12);

    // ---- output MLP: fused 128 -> 128 -> 2 ----
    lo_fused_kernel<<<16384 / 32, 256, 0, stream>>>(xfA,
        lo_w1, lo_b1, lo_g1, lo_be1, lo_w2, lo_b2, lo_g2, lo_be2,
        (float*)d_out);
}